// Round 10
// baseline (17498.431 us; speedup 1.0000x reference)
//
#include <hip/hip_runtime.h>
#include <stdint.h>
#include <math.h>

typedef unsigned short u16;
typedef unsigned long long u64;
typedef short s16x8 __attribute__((ext_vector_type(8)));
typedef __bf16 bv8 __attribute__((ext_vector_type(8)));
typedef float f32x4 __attribute__((ext_vector_type(4)));

#define DEV static __device__ __forceinline__

DEV float b2f(u16 x){ union{unsigned u; float f;} v; v.u=((unsigned)x)<<16; return v.f; }
DEV u16 f2b(float f){ union{float f; unsigned u;} v; v.f=f; unsigned u=v.u; u += 0x7fff + ((u>>16)&1u); return (u16)(u>>16); }
DEV float sigm(float x){ return 1.f/(1.f+__expf(-x)); }
DEV float tanh_(float x){ float cx=fminf(fmaxf(x,-20.f),20.f); float e=__expf(2.f*cx); return (e-1.f)/(e+1.f); }
DEV f32x4 mfma16(bv8 a, bv8 b, f32x4 c){ return __builtin_amdgcn_mfma_f32_16x16x32_bf16(a,b,c,0,0,0); }
DEV bv8 ldf(const u16* p){ return __builtin_bit_cast(bv8, *(const s16x8*)p); }
DEV bv8 cvt(const s16x8& v){ return __builtin_bit_cast(bv8, v); }

DEV unsigned ald4(const unsigned* p){ return __hip_atomic_load(p, __ATOMIC_RELAXED, __HIP_MEMORY_SCOPE_AGENT); }

// sc0 load: bypass L1 (used by enc's pipelined h loads; correctness from the acquire fence).
DEV void gld16(s16x8& d, const u16* p){
  asm volatile("global_load_dwordx4 %0, %1, off sc0" : "=&v"(d) : "v"(p));
}
template<int N> DEV void wvm(){
  asm volatile("s_waitcnt vmcnt(%0)" :: "i"(N) : "memory");
  __builtin_amdgcn_sched_barrier(0);
}

// fence-once protocol (proven r6/r8): plain cached state traffic; one wb on arrive, one inv on wait.
DEV void arrive(unsigned* flags, int my, unsigned e){
  __syncthreads();
  if (threadIdx.x < 64){
    __builtin_amdgcn_fence(__ATOMIC_RELEASE, "agent");
    if (threadIdx.x == 0)
      __hip_atomic_store(&flags[my*32], e, __ATOMIC_RELAXED, __HIP_MEMORY_SCOPE_AGENT);
  }
}
DEV void waitflags(unsigned* flags, int lo, int n, unsigned e){
  int t = (int)threadIdx.x;
  if (t>=lo && t<lo+n){
    while (ald4(&flags[t*32]) < e) __builtin_amdgcn_s_sleep(1);
  }
  if (t < 64) __builtin_amdgcn_fence(__ATOMIC_ACQUIRE, "agent");
  __syncthreads();
}

// ---------------- weight f32 -> bf16 conversion ----------------
struct CvtJobs { const float* s[14]; u16* d[14]; int start[14]; };

__global__ __launch_bounds__(256) void cvt_w(CvtJobs J){
  int blk = blockIdx.x, tid = threadIdx.x;
  int j = 0;
  #pragma unroll
  for (int k=1;k<14;k++) if (blk >= J.start[k]) j = k;
  size_t idx = (size_t)(blk - J.start[j])*2048 + (size_t)tid*8;
  const f32x4* ps = (const f32x4*)(J.s[j] + idx);
  f32x4 a = ps[0], b = ps[1];
  s16x8 o;
  #pragma unroll
  for (int i=0;i<4;i++){ o[i]=(short)f2b(a[i]); o[4+i]=(short)f2b(b[i]); }
  *(s16x8*)(J.d[j] + idx) = o;
}

__global__ __launch_bounds__(256) void tr_w2d(const u16* __restrict__ in, u16* __restrict__ out){
  int idx = blockIdx.x*256 + threadIdx.x;  // 32768
  int r = idx>>7, p = idx&127;
  out[idx] = in[p*256 + r];
}

__global__ __launch_bounds__(256) void pb_k(const float* __restrict__ Wihd, const float* __restrict__ b2d,
                                            float* __restrict__ pb){
  int g = blockIdx.x*256 + threadIdx.x;    // 2048
  const float* row = Wihd + (size_t)g*384 + 256;
  float s = 0.f;
  for (int p=0;p<128;p++) s += row[p]*b2d[p];
  pb[g] = s;
}

// ---------------- LayerNorm stats ----------------
__global__ __launch_bounds__(256) void ln_stats(const float* __restrict__ x,
                                                float* __restrict__ mu, float* __restrict__ rstd){
  int b = blockIdx.x;
  const float* xb = x + (size_t)b*32768;
  float s1=0.f, s2=0.f;
  for (int i = threadIdx.x*4; i < 32768; i += 256*4){
    f32x4 v = *(const f32x4*)(xb+i);
    #pragma unroll
    for (int j=0;j<4;j++){ float f = v[j]; s1+=f; s2+=f*f; }
  }
  #pragma unroll
  for (int o=32;o>0;o>>=1){ s1 += __shfl_down(s1,o); s2 += __shfl_down(s2,o); }
  __shared__ float r1[4], r2[4];
  int w = threadIdx.x>>6;
  if ((threadIdx.x&63)==0){ r1[w]=s1; r2[w]=s2; }
  __syncthreads();
  if (threadIdx.x==0){
    float a=0.f,c=0.f;
    for (int i=0;i<4;i++){ a+=r1[i]; c+=r2[i]; }
    float m=a/32768.f, v=c/32768.f-m*m;
    mu[b]=m; rstd[b]=1.f/sqrtf(v+1e-5f);
  }
}

// ---------------- fused LN + encode GEMM ----------------
__global__ __launch_bounds__(256) void ln_gemm(const float* __restrict__ x,
    const float* __restrict__ mu, const float* __restrict__ rstd,
    const float* __restrict__ g, const float* __restrict__ bn,
    const u16* __restrict__ Wb, const float* __restrict__ be, u16* __restrict__ xe){
  __shared__ __align__(16) u16 As[128*32];
  __shared__ __align__(16) u16 Ws[128*32];
  int tid=threadIdx.x, lane=tid&63, wid=tid>>6;
  int wr=wid>>1, wc=wid&1;
  long m0=(long)blockIdx.y*128, n0=(long)blockIdx.x*128;
  int lr=lane&15, lk=(lane>>4)*8;
  f32x4 acc[4][4];
  #pragma unroll
  for (int i=0;i<4;i++)
    #pragma unroll
    for (int j=0;j<4;j++) acc[i][j]=(f32x4){0.f,0.f,0.f,0.f};

  for (int k0=0;k0<128;k0+=32){
    __syncthreads();
    #pragma unroll
    for (int c=tid;c<512;c+=256){
      int row=c>>2, kb=(c&3)*8;
      long R=m0+row;
      int b=(int)(R>>8), tt=(int)(R&255);
      float m=mu[b], rs=rstd[b];
      const f32x4* px=(const f32x4*)(x + R*128 + k0+kb);
      const f32x4* pg=(const f32x4*)(g + tt*128 + k0+kb);
      const f32x4* pb=(const f32x4*)(bn + tt*128 + k0+kb);
      f32x4 x0=px[0], x1=px[1], g0=pg[0], g1=pg[1], b0=pb[0], b1=pb[1];
      s16x8 o;
      #pragma unroll
      for (int j=0;j<4;j++){
        o[j]   = (short)f2b((x0[j]-m)*rs*g0[j] + b0[j]);
        o[4+j] = (short)f2b((x1[j]-m)*rs*g1[j] + b1[j]);
      }
      *(s16x8*)(As + row*32 + kb) = o;
    }
    #pragma unroll
    for (int c=tid;c<512;c+=256){
      int row=c>>2, kb=(c&3)*8;
      *(s16x8*)(Ws + row*32 + kb) = *(const s16x8*)(Wb + (n0+row)*128 + k0+kb);
    }
    __syncthreads();
    bv8 af[4], bf[4];
    #pragma unroll
    for (int i=0;i<4;i++) af[i] = ldf(As + (wr*64+i*16+lr)*32 + lk);
    #pragma unroll
    for (int j=0;j<4;j++) bf[j] = ldf(Ws + (wc*64+j*16+lr)*32 + lk);
    #pragma unroll
    for (int i=0;i<4;i++)
      #pragma unroll
      for (int j=0;j<4;j++) acc[i][j] = mfma16(af[i], bf[j], acc[i][j]);
  }
  #pragma unroll
  for (int i=0;i<4;i++)
    #pragma unroll
    for (int j=0;j<4;j++)
      #pragma unroll
      for (int r=0;r<4;r++){
        int m = wr*64+i*16+(lane>>4)*4+r;
        int n = wc*64+j*16+lr;
        float v = acc[i][j][r] + be[n0+n];
        xe[(m0+m)*256 + n0+n] = f2b(fmaxf(v,0.f));
      }
}

// ---------------- generic GEMM ----------------
template<int BM, int BN, bool RELU, bool OUTF32>
__global__ __launch_bounds__(256) void gemm_bt(const u16* __restrict__ A, int lda,
                                               const u16* __restrict__ W, int ldw,
                                               const float* __restrict__ bias1, const float* __restrict__ bias2,
                                               u16* __restrict__ Cb, float* __restrict__ Cf, int ldc, int K){
  constexpr int BK=32;
  constexpr int FM=BM/32, FN=BN/32;
  __shared__ __align__(16) u16 As[BM*BK];
  __shared__ __align__(16) u16 Ws[BN*BK];
  int tid=threadIdx.x, lane=tid&63, wid=tid>>6;
  int wr=wid>>1, wc=wid&1;
  long m0=(long)blockIdx.y*BM, n0=(long)blockIdx.x*BN;
  int lr=lane&15, lk=(lane>>4)*8;
  f32x4 acc[FM][FN];
  #pragma unroll
  for (int i=0;i<FM;i++)
    #pragma unroll
    for (int j=0;j<FN;j++) acc[i][j] = (f32x4){0.f,0.f,0.f,0.f};
  for (int k0=0;k0<K;k0+=BK){
    __syncthreads();
    #pragma unroll
    for (int c=tid;c<BM*4;c+=256){
      int row=c>>2, kb=(c&3)*8;
      *(s16x8*)(As + row*BK + kb) = *(const s16x8*)(A + (m0+row)*lda + k0+kb);
    }
    #pragma unroll
    for (int c=tid;c<BN*4;c+=256){
      int row=c>>2, kb=(c&3)*8;
      *(s16x8*)(Ws + row*BK + kb) = *(const s16x8*)(W + (n0+row)*ldw + k0+kb);
    }
    __syncthreads();
    bv8 af[FM], bf[FN];
    #pragma unroll
    for (int i=0;i<FM;i++) af[i] = ldf(As + (wr*(BM/2)+i*16+lr)*BK + lk);
    #pragma unroll
    for (int j=0;j<FN;j++) bf[j] = ldf(Ws + (wc*(BN/2)+j*16+lr)*BK + lk);
    #pragma unroll
    for (int i=0;i<FM;i++)
      #pragma unroll
      for (int j=0;j<FN;j++) acc[i][j] = mfma16(af[i], bf[j], acc[i][j]);
  }
  #pragma unroll
  for (int i=0;i<FM;i++)
    #pragma unroll
    for (int j=0;j<FN;j++)
      #pragma unroll
      for (int r=0;r<4;r++){
        int m = wr*(BM/2)+i*16+(lane>>4)*4+r;
        int n = wc*(BN/2)+j*16+lr;
        float v = acc[i][j][r];
        if (bias1) v += bias1[n0+n];
        if (bias2) v += bias2[n0+n];
        if (RELU) v = fmaxf(v,0.f);
        if (OUTF32) Cf[(m0+m)*ldc + n0+n] = v;
        else        Cb[(m0+m)*ldc + n0+n] = f2b(v);
      }
}

// ================= persistent encoder (r8-proven, unchanged) =================
// grid 256: grp = bx&7 (dir*4+bt), kc = bx>>3 (16 cells)
struct EncP {
  const u16* xe; const int* lens;
  const u16 *Wihf,*Whhf,*Wihb,*Whhb;
  const float *bif,*bhf,*bib,*bhb;
  u16 *hf0,*hf1,*hb0,*hb1,*pooled;
  unsigned* flags;
};

__global__ __launch_bounds__(256,1) void enc_persist(EncP P){
  __shared__ __align__(16) u16 Wl[64*776];
  __shared__ __align__(16) u16 Hs[128*16];
  const int tid=threadIdx.x, lane=tid&63, w=tid>>6;
  const int bx=blockIdx.x;
  const int grp=bx&7, kc=bx>>3;
  const int dir=grp>>2, bt=grp&3;
  const int lr=lane&15, lk=(lane>>4)*8;
  unsigned* flags = P.flags + grp*2048;
  const u16* Wih = dir? P.Wihb : P.Wihf;
  const u16* Whh = dir? P.Whhb : P.Whhf;
  const float* bi = dir? P.bib : P.bif;
  const float* bh = dir? P.bhb : P.bhf;
  u16* h0 = dir? P.hb0 : P.hf0;
  u16* h1 = dir? P.hb1 : P.hf1;

  for (int idx=tid; idx<64*96; idx+=256){
    int row=idx/96, col=(idx%96)*8;
    int g=row>>4, c=row&15;
    size_t grow=(size_t)(g*512 + kc*16 + c);
    const u16* src = (col<256)? (Wih + grow*256 + col) : (Whh + grow*512 + (col-256));
    *(s16x8*)(Wl + row*776 + col) = *(const s16x8*)src;
  }
  const int cg = kc*16 + lr;
  const float b_i=bi[cg]+bh[cg], b_f=bi[512+cg]+bh[512+cg];
  const float b_g=bi[1024+cg]+bh[1024+cg], b_o=bi[1536+cg]+bh[1536+cg];
  const int r0 = w*32 + lr, r1i = r0 + 16;
  const int slen0 = P.lens[bt*128+r0], slen1 = P.lens[bt*128+r1i];
  const u16* xb0 = P.xe + (size_t)(bt*128+r0)*65536;
  const u16* xb1 = P.xe + (size_t)(bt*128+r1i)*65536;
  int elen[2][4]; float cs[2][4], hh[2][4], asum[2][4];
  #pragma unroll
  for (int i=0;i<2;i++)
    #pragma unroll
    for (int r=0;r<4;r++){
      int m=w*32+i*16+(lane>>4)*4+r;
      elen[i][r]=P.lens[bt*128+m];
      cs[i][r]=0.f; hh[i][r]=0.f; asum[i][r]=0.f;
    }
  __syncthreads();   // weights staged

  auto xpart=[&](int t_, f32x4 (&xacc)[2][4]){
    int tt0 = dir? max(slen0-1-t_,0) : t_;
    int tt1 = dir? max(slen1-1-t_,0) : t_;
    const u16* xr0 = xb0 + (size_t)tt0*256;
    const u16* xr1 = xb1 + (size_t)tt1*256;
    #pragma unroll
    for (int k=0;k<4;k++)
      #pragma unroll
      for (int kk=0;kk<2;kk++){
        bv8 a0 = ldf(xr0 + k*64 + kk*32 + lk);
        bv8 a1 = ldf(xr1 + k*64 + kk*32 + lk);
        #pragma unroll
        for (int g=0;g<4;g++){
          bv8 bf = ldf(Wl + (g*16+lr)*776 + k*64 + kk*32 + lk);
          xacc[0][g]=mfma16(a0,bf,xacc[0][g]);
          xacc[1][g]=mfma16(a1,bf,xacc[1][g]);
        }
      }
  };

  f32x4 xacc[2][4];
  #pragma unroll
  for (int i=0;i<2;i++)
    #pragma unroll
    for (int g=0;g<4;g++) xacc[i][g]=(f32x4){0.f,0.f,0.f,0.f};
  xpart(0, xacc);

  for (int t=0;t<256;t++){
    const u16* hp = (t&1)? h1 : h0;
    u16*       hn = (t&1)? h0 : h1;
    waitflags(flags, 0, 32, (unsigned)t);
    f32x4 acc[2][4];
    #pragma unroll
    for (int i=0;i<2;i++)
      #pragma unroll
      for (int g=0;g<4;g++) acc[i][g]=xacc[i][g];
    {
      const u16* hr0 = hp + (size_t)(bt*128+r0)*512;
      const u16* hr1 = hp + (size_t)(bt*128+r1i)*512;
      s16x8 fb[2][8];
      auto issue=[&](int b, int k2){
        const u16* p0 = hr0 + k2*128;
        const u16* p1 = hr1 + k2*128;
        gld16(fb[b][0], p0+lk);    gld16(fb[b][1], p1+lk);
        gld16(fb[b][2], p0+32+lk); gld16(fb[b][3], p1+32+lk);
        gld16(fb[b][4], p0+64+lk); gld16(fb[b][5], p1+64+lk);
        gld16(fb[b][6], p0+96+lk); gld16(fb[b][7], p1+96+lk);
      };
      issue(0,0); issue(1,1);
      #pragma unroll
      for (int k2=0;k2<4;k2++){
        if (k2<3) wvm<8>(); else wvm<0>();
        const int b=k2&1;
        #pragma unroll
        for (int dk=0;dk<2;dk++)
          #pragma unroll
          for (int kk=0;kk<2;kk++){
            bv8 a0=cvt(fb[b][dk*4+kk*2]), a1=cvt(fb[b][dk*4+kk*2+1]);
            #pragma unroll
            for (int g=0;g<4;g++){
              bv8 bf=ldf(Wl + (g*16+lr)*776 + 256 + (2*k2+dk)*64 + kk*32 + lk);
              acc[0][g]=mfma16(a0,bf,acc[0][g]);
              acc[1][g]=mfma16(a1,bf,acc[1][g]);
            }
          }
        if (k2<2) issue(k2&1, k2+2);
      }
    }
    #pragma unroll
    for (int i=0;i<2;i++)
      #pragma unroll
      for (int r=0;r<4;r++){
        int m=w*32+i*16+(lane>>4)*4+r;
        if (t<elen[i][r]){
          float iv=sigm(acc[i][0][r]+b_i), fv=sigm(acc[i][1][r]+b_f);
          float gv=tanh_(acc[i][2][r]+b_g), ov=sigm(acc[i][3][r]+b_o);
          float c2=fv*cs[i][r]+iv*gv, h2v=ov*tanh_(c2);
          cs[i][r]=c2; hh[i][r]=h2v; asum[i][r]+=h2v;
        }
        Hs[m*16+lr]=f2b(hh[i][r]);
      }
    __syncthreads();
    #pragma unroll
    for (int q=0;q<2;q++){
      int cc=tid*2+q, sm=cc>>2, pt=cc&3;
      *(u64*)(hn + (size_t)(bt*128+sm)*512 + kc*16 + pt*4) = *(const u64*)(Hs + sm*16 + pt*4);
    }
    arrive(flags, kc, (unsigned)(t+1));
    #pragma unroll
    for (int i=0;i<2;i++)
      #pragma unroll
      for (int g=0;g<4;g++) xacc[i][g]=(f32x4){0.f,0.f,0.f,0.f};
    if (t<255) xpart(t+1, xacc);
  }
  #pragma unroll
  for (int i=0;i<2;i++)
    #pragma unroll
    for (int r=0;r<4;r++){
      int m=w*32+i*16+(lane>>4)*4+r;
      P.pooled[(size_t)(bt*128+m)*1024 + (size_t)dir*512 + cg]=f2b(asum[i][r]/(float)elen[i][r]);
    }
}

// ================= persistent decoder — ONE hop/step via redundant r1 =================
// grid 256: grp=bx&7 (64 samples), kc=bx>>3 (16 cells / 64 gate rows).
// step t>=1: wait h_t; each wave computes r1 outputs [64w,64w+64) for ALL 64 samples
// (W1d streamed from L2, read once per block); bounce r1 through LDS; gates = gix+pb
// + Whh.h_t + Wcomp.r1; cell -> h_{t+1}; publish; arrive. kc in [16,24): pose from own
// r1 copy -> outd[t-1] in the shadow. W1d: [256 rows x 512]; Wcomp: [2048 x 256].
struct DecP {
  const u16 *Whhd, *Wcmp, *W1d, *W2d;
  const float *gix, *gp0, *pb, *b1d, *b2d;
  u16 *h0,*h1;
  float* outd;
  unsigned* flags;
};

__global__ __launch_bounds__(256,1) void dec_persist(DecP P){
  __shared__ __align__(16) u16 Wh [64*520];
  __shared__ __align__(16) u16 WcL[64*264];
  __shared__ __align__(16) u16 F2s[16*264];
  __shared__ __align__(16) u16 r1s[64*264];
  __shared__ __align__(16) u16 Hs[64*16];
  const int tid=threadIdx.x, lane=tid&63, w=tid>>6;
  const int bx=blockIdx.x;
  const int grp=bx&7, kc=bx>>3;
  const int g0 = grp*64;
  const int lr=lane&15, lk=(lane>>4)*8;
  unsigned* flags = P.flags + grp*2048;

  for (int idx=tid; idx<64*64; idx+=256){
    int row=idx>>6, col=(idx&63)*8;
    int g=row>>4, c=row&15;
    size_t grow=(size_t)(g*512+kc*16+c);
    *(s16x8*)(Wh + row*520 + col) = *(const s16x8*)(P.Whhd + grow*512 + col);
  }
  for (int idx=tid; idx<64*32; idx+=256){
    int row=idx>>5, col=(idx&31)*8;
    int g=row>>4, c=row&15;
    size_t grow=(size_t)(g*512+kc*16+c);
    *(s16x8*)(WcL + row*264 + col) = *(const s16x8*)(P.Wcmp + grow*256 + col);
  }
  if (kc>=16 && kc<24){
    for (int idx=tid; idx<16*32; idx+=256){
      int rr=idx>>5, col=(idx&31)*8;
      *(s16x8*)(F2s + rr*264 + col) = *(const s16x8*)(P.W2d + (size_t)((kc-16)*16+rr)*256 + col);
    }
  }
  float gx[4][4]; float pbr[4]; float b1v[4];
  #pragma unroll
  for (int g=0;g<4;g++)
    #pragma unroll
    for (int r=0;r<4;r++){
      int m=w*16+(lane>>4)*4+r;
      gx[g][r]=P.gix[(size_t)(g0+m)*2048 + (size_t)g*512 + kc*16 + lr];
    }
  #pragma unroll
  for (int g=0;g<4;g++) pbr[g] = P.pb[(size_t)g*512 + kc*16 + lr];
  #pragma unroll
  for (int n2=0;n2<4;n2++) b1v[n2] = P.b1d[w*64 + n2*16 + lr];
  const float b2=(kc>=16&&kc<24)? P.b2d[(kc-16)*16+lr] : 0.f;
  float cs[4];
  #pragma unroll
  for (int r=0;r<4;r++) cs[r]=0.f;
  __syncthreads();   // weights staged

  // computes full r1 (this wave's 64-output slice) + this block's Whh gates, from h rows.
  auto window=[&](const u16* hbase, f32x4 (&racc)[4][4], f32x4* accg /*4 or null*/){
    #pragma unroll
    for (int mi=0;mi<4;mi++)
      #pragma unroll
      for (int n2=0;n2<4;n2++) racc[mi][n2]=(f32x4){0.f,0.f,0.f,0.f};
    #pragma unroll
    for (int kk=0;kk<16;kk++){
      bv8 a[4];
      #pragma unroll
      for (int mi=0;mi<4;mi++)
        a[mi] = ldf(hbase + (size_t)(g0 + mi*16 + lr)*512 + kk*32 + lk);
      #pragma unroll
      for (int n2=0;n2<4;n2++){
        bv8 bf = ldf(P.W1d + (size_t)(w*64 + n2*16 + lr)*512 + kk*32 + lk);
        #pragma unroll
        for (int mi=0;mi<4;mi++) racc[mi][n2]=mfma16(a[mi], bf, racc[mi][n2]);
      }
      if (accg){
        #pragma unroll
        for (int g=0;g<4;g++){
          bv8 bf = ldf(Wh + (g*16+lr)*520 + kk*32 + lk);
          accg[g]=mfma16(a[w], bf, accg[g]);
        }
      }
    }
    // r1 -> LDS (relu + b1), cols w*64..w*64+63 for all 64 samples
    #pragma unroll
    for (int mi=0;mi<4;mi++)
      #pragma unroll
      for (int n2=0;n2<4;n2++)
        #pragma unroll
        for (int r=0;r<4;r++){
          int sm = mi*16 + (lane>>4)*4 + r;
          int cn = w*64 + n2*16 + lr;
          r1s[sm*264 + cn] = f2b(fmaxf(racc[mi][n2][r] + b1v[n2], 0.f));
        }
    __syncthreads();
  };

  for (int t=0;t<256;t++){
    const u16* hp = (t&1)? P.h1 : P.h0;   // h_t (published at iter t-1)
    u16*       hn = (t&1)? P.h0 : P.h1;   // h_{t+1}
    f32x4 acc[4];
    if (t==0){
      #pragma unroll
      for (int g=0;g<4;g++)
        #pragma unroll
        for (int r=0;r<4;r++){
          int m=w*16+(lane>>4)*4+r;
          acc[g][r] = gx[g][r] + P.gp0[(size_t)(g0+m)*2048 + (size_t)g*512 + kc*16 + lr];
        }
    } else {
      waitflags(flags, 0, 32, (unsigned)t);
      #pragma unroll
      for (int g=0;g<4;g++){
        acc[g] = (f32x4){gx[g][0]+pbr[g], gx[g][1]+pbr[g], gx[g][2]+pbr[g], gx[g][3]+pbr[g]};
      }
      f32x4 racc[4][4];
      window(hp, racc, acc);            // adds Whh.h_t into acc, fills r1s
      // Wcomp . r1 (K=256) from LDS
      #pragma unroll
      for (int kk=0;kk<8;kk++){
        bv8 a2 = ldf(r1s + (w*16+lr)*264 + kk*32 + lk);
        #pragma unroll
        for (int g=0;g<4;g++){
          bv8 bf=ldf(WcL + (g*16+lr)*264 + kk*32 + lk);
          acc[g]=mfma16(a2,bf,acc[g]);
        }
      }
    }
    // cell
    #pragma unroll
    for (int r=0;r<4;r++){
      float iv=sigm(acc[0][r]), fv=sigm(acc[1][r]);
      float gv=tanh_(acc[2][r]), ov=sigm(acc[3][r]);
      float c2=fv*cs[r]+iv*gv, h2v=ov*tanh_(c2);
      cs[r]=c2;
      int m=w*16+(lane>>4)*4+r;
      Hs[m*16+lr]=f2b(h2v);
    }
    __syncthreads();
    {
      int sm=tid>>2, pt=tid&3;
      *(u64*)(hn + (size_t)(g0+sm)*512 + kc*16 + pt*4) = *(const u64*)(Hs + sm*16 + pt*4);
    }
    arrive(flags, kc, (unsigned)(t+1));
    // shadow: pose_t = W2d.r1(h_t) + b2 -> outd[t-1]  (F2 blocks, own r1 copy in LDS)
    if (kc>=16 && kc<24 && t>0){
      f32x4 fa2=(f32x4){0.f,0.f,0.f,0.f};
      #pragma unroll
      for (int kk=0;kk<8;kk++){
        bv8 a2 = ldf(r1s + (w*16+lr)*264 + kk*32 + lk);
        bv8 bf = ldf(F2s + lr*264 + kk*32 + lk);
        fa2=mfma16(a2,bf,fa2);
      }
      int pc=(kc-16)*16+lr;
      #pragma unroll
      for (int r=0;r<4;r++){
        int m=w*16+(lane>>4)*4+r;
        __builtin_nontemporal_store(fa2[r]+b2, P.outd + (size_t)(g0+m)*32768 + (size_t)(t-1)*128 + pc);
      }
    }
  }
  // epilogue: outd[255] = pose_256 = W2d.relu(W1d.h_256 + b1) + b2
  if (kc>=16 && kc<24){
    waitflags(flags, 0, 32, 256u);
    f32x4 racc[4][4];
    window(P.h0, racc, nullptr);        // h_256 parity: published at t=255 -> h0
    f32x4 fa2=(f32x4){0.f,0.f,0.f,0.f};
    #pragma unroll
    for (int kk=0;kk<8;kk++){
      bv8 a2 = ldf(r1s + (w*16+lr)*264 + kk*32 + lk);
      bv8 bf = ldf(F2s + lr*264 + kk*32 + lk);
      fa2=mfma16(a2,bf,fa2);
    }
    int pc=(kc-16)*16+lr;
    #pragma unroll
    for (int r=0;r<4;r++){
      int m=w*16+(lane>>4)*4+r;
      __builtin_nontemporal_store(fa2[r]+b2, P.outd + (size_t)(g0+m)*32768 + (size_t)255*128 + pc);
    }
  }
}

__global__ __launch_bounds__(512) void len_cast(const int* __restrict__ lens, float* __restrict__ out){
  int i = threadIdx.x;
  if (i < 512) out[i] = (float)lens[i];
}

// ============================== host ==============================
extern "C" void kernel_launch(void* const* d_in, const int* in_sizes, int n_in,
                              void* d_out, int out_size, void* d_ws, size_t ws_size,
                              hipStream_t stream){
  (void)in_sizes; (void)n_in; (void)out_size; (void)ws_size;
  const float* x      = (const float*)d_in[0];
  const int*   lens   = (const int*)d_in[1];
  const float* ng     = (const float*)d_in[2];
  const float* nb     = (const float*)d_in[3];
  const float* We     = (const float*)d_in[4];
  const float* be     = (const float*)d_in[5];
  const float* Wih_f  = (const float*)d_in[6];
  const float* Whh_f  = (const float*)d_in[7];
  const float* bih_f  = (const float*)d_in[8];
  const float* bhh_f  = (const float*)d_in[9];
  const float* Wih_b  = (const float*)d_in[10];
  const float* Whh_b  = (const float*)d_in[11];
  const float* bih_b  = (const float*)d_in[12];
  const float* bhh_b  = (const float*)d_in[13];
  const float* W1e    = (const float*)d_in[14];
  const float* b1e    = (const float*)d_in[15];
  const float* W2e    = (const float*)d_in[16];
  const float* b2e    = (const float*)d_in[17];
  const float* Wd     = (const float*)d_in[18];
  const float* bd     = (const float*)d_in[19];
  const float* Wp1    = (const float*)d_in[20];
  const float* bp1    = (const float*)d_in[21];
  const float* Wp2    = (const float*)d_in[22];
  const float* bp2    = (const float*)d_in[23];
  const float* Wih_d  = (const float*)d_in[24];
  const float* Whh_d  = (const float*)d_in[25];
  const float* bih_d  = (const float*)d_in[26];
  const float* bhh_d  = (const float*)d_in[27];
  const float* W1d    = (const float*)d_in[28];
  const float* b1d    = (const float*)d_in[29];
  const float* W2d    = (const float*)d_in[30];
  const float* b2d    = (const float*)d_in[31];

  char* p = (char*)d_ws;
  auto carve = [&](size_t bytes)->void*{ void* r=(void*)p; p += (bytes+255)&~(size_t)255; return r; };
  float* mu   = (float*)carve(512*4);
  float* rstd = (float*)carve(512*4);
  u16* xe     = (u16*)carve((size_t)33554432*2);
  u16* wWe  = (u16*)carve(32768*2);
  u16* wIhf = (u16*)carve(524288*2);
  u16* wHhf = (u16*)carve(1048576*2);
  u16* wIhb = (u16*)carve(524288*2);
  u16* wHhb = (u16*)carve(1048576*2);
  u16* wW1e = (u16*)carve(524288*2);
  u16* wW2e = (u16*)carve(131072*2);
  u16* wWd  = (u16*)carve(65536*2);
  u16* wWp1 = (u16*)carve(65536*2);
  u16* wWp2 = (u16*)carve(32768*2);
  u16* wIhd = (u16*)carve(786432*2);
  u16* wHhd = (u16*)carve(1048576*2);
  u16* wW1d = (u16*)carve(131072*2);
  u16* wW2d = (u16*)carve(32768*2);
  u16* wW2dT  = (u16*)carve(32768*2);
  u16* wWcomp = (u16*)carve(524288*2);
  float* pbv  = (float*)carve(2048*4);
  float* gp0f = (float*)carve((size_t)1048576*4);
  u16* hf0  = (u16*)carve(524288);
  u16* hf1  = (u16*)carve(524288);
  u16* hb0  = (u16*)carve(524288);
  u16* hb1  = (u16*)carve(524288);
  u16* hd0  = (u16*)carve(524288);
  u16* hd1  = (u16*)carve(524288);
  u16* pooled = (u16*)carve(1048576);
  u16* out1   = (u16*)carve(524288);
  u16* zlat   = (u16*)carve(262144);
  u16* x0     = (u16*)carve(262144);
  u16* t0     = (u16*)carve(262144);
  float* gix  = (float*)carve(4194304);
  u16* pose   = (u16*)carve(131072);
  unsigned* barflags = (unsigned*)carve(16*2048*4);

  float* out_x   = (float*)d_out;
  float* out_dec = out_x + 16777216;
  float* out_len = out_x + 33554432;

  hipMemcpyAsync(out_x, x, (size_t)16777216*4, hipMemcpyDeviceToDevice, stream);
  hipMemsetAsync(hf0,0,524288,stream);
  hipMemsetAsync(hb0,0,524288,stream);
  hipMemsetAsync(barflags,0,16*2048*4,stream);

  CvtJobs J;
  const float* srcs[14] = {We,Wih_f,Whh_f,Wih_b,Whh_b,W1e,W2e,Wd,Wp1,Wp2,Wih_d,Whh_d,W1d,W2d};
  u16* dsts[14] = {wWe,wIhf,wHhf,wIhb,wHhb,wW1e,wW2e,wWd,wWp1,wWp2,wIhd,wHhd,wW1d,wW2d};
  int ns[14] = {32768,524288,1048576,524288,1048576,524288,131072,65536,65536,32768,786432,1048576,131072,32768};
  int blk=0;
  for (int i=0;i<14;i++){ J.s[i]=srcs[i]; J.d[i]=dsts[i]; J.start[i]=blk; blk += ns[i]/2048; }
  cvt_w<<<blk,256,0,stream>>>(J);

  tr_w2d<<<128,256,0,stream>>>(wW2d, wW2dT);
  pb_k<<<8,256,0,stream>>>(Wih_d, b2d, pbv);
  gemm_bt<64,64,false,false><<<dim3(4,32),256,0,stream>>>(wIhd+256,384, wW2dT,128, nullptr,nullptr, wWcomp,nullptr,256,128);

  ln_stats<<<512,256,0,stream>>>(x,mu,rstd);
  ln_gemm<<<dim3(2,1024),256,0,stream>>>(x,mu,rstd,ng,nb,wWe,be,xe);

  EncP EP = {xe,lens,wIhf,wHhf,wIhb,wHhb,bih_f,bhh_f,bih_b,bhh_b,hf0,hf1,hb0,hb1,pooled,barflags};
  {
    void* ea[] = {&EP};
    if (hipLaunchCooperativeKernel((void*)enc_persist, dim3(256), dim3(256), ea, 0, stream) != hipSuccess)
      enc_persist<<<256,256,0,stream>>>(EP);
  }

  gemm_bt<64,64,true ,false><<<dim3(8,8),256,0,stream>>>(pooled,1024,wW1e,1024,b1e,nullptr,out1,nullptr,512,1024);
  gemm_bt<64,64,false,false><<<dim3(4,8),256,0,stream>>>(out1,512,wW2e,512,b2e,nullptr,zlat,nullptr,256,512);
  gemm_bt<64,64,true ,false><<<dim3(4,8),256,0,stream>>>(zlat,256,wWd,256,bd,nullptr,x0,nullptr,256,256);
  gemm_bt<64,64,true ,false><<<dim3(4,8),256,0,stream>>>(x0,256,wWp1,256,bp1,nullptr,t0,nullptr,256,256);
  gemm_bt<64,64,false,false><<<dim3(2,8),256,0,stream>>>(t0,256,wWp2,256,bp2,nullptr,pose,nullptr,128,256);
  gemm_bt<64,128,false,true><<<dim3(16,8),256,0,stream>>>(x0,256,wIhd,384,bih_d,bhh_d,nullptr,gix,2048,256);
  gemm_bt<64,128,false,true><<<dim3(16,8),256,0,stream>>>(pose,128,wIhd+256,384,nullptr,nullptr,nullptr,gp0f,2048,128);

  DecP DP = {wHhd,wWcomp,wW1d,wW2d, gix,gp0f,pbv,b1d,b2d, hd0,hd1, out_dec, barflags + 8*2048};
  {
    void* da[] = {&DP};
    if (hipLaunchCooperativeKernel((void*)dec_persist, dim3(256), dim3(256), da, 0, stream) != hipSuccess)
      dec_persist<<<256,256,0,stream>>>(DP);
  }

  len_cast<<<1,512,0,stream>>>(lens,out_len);
}

// Round 11
// 4378.960 us; speedup vs baseline: 3.9960x; 3.9960x over previous
//
#include <hip/hip_runtime.h>
#include <stdint.h>
#include <math.h>

typedef unsigned short u16;
typedef unsigned long long u64;
typedef short s16x8 __attribute__((ext_vector_type(8)));
typedef __bf16 bv8 __attribute__((ext_vector_type(8)));
typedef float f32x4 __attribute__((ext_vector_type(4)));

#define DEV static __device__ __forceinline__

DEV float b2f(u16 x){ union{unsigned u; float f;} v; v.u=((unsigned)x)<<16; return v.f; }
DEV u16 f2b(float f){ union{float f; unsigned u;} v; v.f=f; unsigned u=v.u; u += 0x7fff + ((u>>16)&1u); return (u16)(u>>16); }
DEV float sigm(float x){ return 1.f/(1.f+__expf(-x)); }
DEV float tanh_(float x){ float cx=fminf(fmaxf(x,-20.f),20.f); float e=__expf(2.f*cx); return (e-1.f)/(e+1.f); }
DEV f32x4 mfma16(bv8 a, bv8 b, f32x4 c){ return __builtin_amdgcn_mfma_f32_16x16x32_bf16(a,b,c,0,0,0); }
DEV bv8 ldf(const u16* p){ return __builtin_bit_cast(bv8, *(const s16x8*)p); }
DEV bv8 cvt(const s16x8& v){ return __builtin_bit_cast(bv8, v); }

DEV unsigned ald4(const unsigned* p){ return __hip_atomic_load(p, __ATOMIC_RELAXED, __HIP_MEMORY_SCOPE_AGENT); }

// sc1 state exchange (r5-proven): loads/stores bypass L1+L2, coherent at L3. No fences anywhere.
DEV void gld16(s16x8& d, const u16* p){
  asm volatile("global_load_dwordx4 %0, %1, off sc0 sc1" : "=&v"(d) : "v"(p));
}
DEV void gst8(u16* p, u64 v){
  asm volatile("global_store_dwordx2 %0, %1, off sc0 sc1" :: "v"(p), "v"(v) : "memory");
}
template<int N> DEV void wvm(){
  asm volatile("s_waitcnt vmcnt(%0)" :: "i"(N) : "memory");
  __builtin_amdgcn_sched_barrier(0);
}

// relaxed flag protocol: ordering = per-thread vmcnt(0) drain (sc1 stores reached L3) + block sync.
DEV void arrive(unsigned* flags, int my, unsigned e){
  asm volatile("s_waitcnt vmcnt(0)" ::: "memory");
  __syncthreads();
  if (threadIdx.x==0)
    __hip_atomic_store(&flags[my*32], e, __ATOMIC_RELAXED, __HIP_MEMORY_SCOPE_AGENT);
}
DEV void waitflags(unsigned* flags, int lo, int n, unsigned e){
  int t = (int)threadIdx.x;
  if (t>=lo && t<lo+n){
    while (ald4(&flags[t*32]) < e) __builtin_amdgcn_s_sleep(1);
  }
  __syncthreads();
}

// ---------------- weight f32 -> bf16 conversion ----------------
struct CvtJobs { const float* s[14]; u16* d[14]; int start[14]; };

__global__ __launch_bounds__(256) void cvt_w(CvtJobs J){
  int blk = blockIdx.x, tid = threadIdx.x;
  int j = 0;
  #pragma unroll
  for (int k=1;k<14;k++) if (blk >= J.start[k]) j = k;
  size_t idx = (size_t)(blk - J.start[j])*2048 + (size_t)tid*8;
  const f32x4* ps = (const f32x4*)(J.s[j] + idx);
  f32x4 a = ps[0], b = ps[1];
  s16x8 o;
  #pragma unroll
  for (int i=0;i<4;i++){ o[i]=(short)f2b(a[i]); o[4+i]=(short)f2b(b[i]); }
  *(s16x8*)(J.d[j] + idx) = o;
}

__global__ __launch_bounds__(256) void tr_w2d(const u16* __restrict__ in, u16* __restrict__ out){
  int idx = blockIdx.x*256 + threadIdx.x;  // 32768
  int r = idx>>7, p = idx&127;
  out[idx] = in[p*256 + r];
}

__global__ __launch_bounds__(256) void pb_k(const float* __restrict__ Wihd, const float* __restrict__ b2d,
                                            float* __restrict__ pb){
  int g = blockIdx.x*256 + threadIdx.x;    // 2048
  const float* row = Wihd + (size_t)g*384 + 256;
  float s = 0.f;
  for (int p=0;p<128;p++) s += row[p]*b2d[p];
  pb[g] = s;
}

// ---------------- LayerNorm stats ----------------
__global__ __launch_bounds__(256) void ln_stats(const float* __restrict__ x,
                                                float* __restrict__ mu, float* __restrict__ rstd){
  int b = blockIdx.x;
  const float* xb = x + (size_t)b*32768;
  float s1=0.f, s2=0.f;
  for (int i = threadIdx.x*4; i < 32768; i += 256*4){
    f32x4 v = *(const f32x4*)(xb+i);
    #pragma unroll
    for (int j=0;j<4;j++){ float f = v[j]; s1+=f; s2+=f*f; }
  }
  #pragma unroll
  for (int o=32;o>0;o>>=1){ s1 += __shfl_down(s1,o); s2 += __shfl_down(s2,o); }
  __shared__ float r1[4], r2[4];
  int w = threadIdx.x>>6;
  if ((threadIdx.x&63)==0){ r1[w]=s1; r2[w]=s2; }
  __syncthreads();
  if (threadIdx.x==0){
    float a=0.f,c=0.f;
    for (int i=0;i<4;i++){ a+=r1[i]; c+=r2[i]; }
    float m=a/32768.f, v=c/32768.f-m*m;
    mu[b]=m; rstd[b]=1.f/sqrtf(v+1e-5f);
  }
}

// ---------------- fused LN + encode GEMM ----------------
__global__ __launch_bounds__(256) void ln_gemm(const float* __restrict__ x,
    const float* __restrict__ mu, const float* __restrict__ rstd,
    const float* __restrict__ g, const float* __restrict__ bn,
    const u16* __restrict__ Wb, const float* __restrict__ be, u16* __restrict__ xe){
  __shared__ __align__(16) u16 As[128*32];
  __shared__ __align__(16) u16 Ws[128*32];
  int tid=threadIdx.x, lane=tid&63, wid=tid>>6;
  int wr=wid>>1, wc=wid&1;
  long m0=(long)blockIdx.y*128, n0=(long)blockIdx.x*128;
  int lr=lane&15, lk=(lane>>4)*8;
  f32x4 acc[4][4];
  #pragma unroll
  for (int i=0;i<4;i++)
    #pragma unroll
    for (int j=0;j<4;j++) acc[i][j]=(f32x4){0.f,0.f,0.f,0.f};

  for (int k0=0;k0<128;k0+=32){
    __syncthreads();
    #pragma unroll
    for (int c=tid;c<512;c+=256){
      int row=c>>2, kb=(c&3)*8;
      long R=m0+row;
      int b=(int)(R>>8), tt=(int)(R&255);
      float m=mu[b], rs=rstd[b];
      const f32x4* px=(const f32x4*)(x + R*128 + k0+kb);
      const f32x4* pg=(const f32x4*)(g + tt*128 + k0+kb);
      const f32x4* pb=(const f32x4*)(bn + tt*128 + k0+kb);
      f32x4 x0=px[0], x1=px[1], g0=pg[0], g1=pg[1], b0=pb[0], b1=pb[1];
      s16x8 o;
      #pragma unroll
      for (int j=0;j<4;j++){
        o[j]   = (short)f2b((x0[j]-m)*rs*g0[j] + b0[j]);
        o[4+j] = (short)f2b((x1[j]-m)*rs*g1[j] + b1[j]);
      }
      *(s16x8*)(As + row*32 + kb) = o;
    }
    #pragma unroll
    for (int c=tid;c<512;c+=256){
      int row=c>>2, kb=(c&3)*8;
      *(s16x8*)(Ws + row*32 + kb) = *(const s16x8*)(Wb + (n0+row)*128 + k0+kb);
    }
    __syncthreads();
    bv8 af[4], bf[4];
    #pragma unroll
    for (int i=0;i<4;i++) af[i] = ldf(As + (wr*64+i*16+lr)*32 + lk);
    #pragma unroll
    for (int j=0;j<4;j++) bf[j] = ldf(Ws + (wc*64+j*16+lr)*32 + lk);
    #pragma unroll
    for (int i=0;i<4;i++)
      #pragma unroll
      for (int j=0;j<4;j++) acc[i][j] = mfma16(af[i], bf[j], acc[i][j]);
  }
  #pragma unroll
  for (int i=0;i<4;i++)
    #pragma unroll
    for (int j=0;j<4;j++)
      #pragma unroll
      for (int r=0;r<4;r++){
        int m = wr*64+i*16+(lane>>4)*4+r;
        int n = wc*64+j*16+lr;
        float v = acc[i][j][r] + be[n0+n];
        xe[(m0+m)*256 + n0+n] = f2b(fmaxf(v,0.f));
      }
}

// ---------------- generic GEMM ----------------
template<int BM, int BN, bool RELU, bool OUTF32>
__global__ __launch_bounds__(256) void gemm_bt(const u16* __restrict__ A, int lda,
                                               const u16* __restrict__ W, int ldw,
                                               const float* __restrict__ bias1, const float* __restrict__ bias2,
                                               u16* __restrict__ Cb, float* __restrict__ Cf, int ldc, int K){
  constexpr int BK=32;
  constexpr int FM=BM/32, FN=BN/32;
  __shared__ __align__(16) u16 As[BM*BK];
  __shared__ __align__(16) u16 Ws[BN*BK];
  int tid=threadIdx.x, lane=tid&63, wid=tid>>6;
  int wr=wid>>1, wc=wid&1;
  long m0=(long)blockIdx.y*BM, n0=(long)blockIdx.x*BN;
  int lr=lane&15, lk=(lane>>4)*8;
  f32x4 acc[FM][FN];
  #pragma unroll
  for (int i=0;i<FM;i++)
    #pragma unroll
    for (int j=0;j<FN;j++) acc[i][j] = (f32x4){0.f,0.f,0.f,0.f};
  for (int k0=0;k0<K;k0+=BK){
    __syncthreads();
    #pragma unroll
    for (int c=tid;c<BM*4;c+=256){
      int row=c>>2, kb=(c&3)*8;
      *(s16x8*)(As + row*BK + kb) = *(const s16x8*)(A + (m0+row)*lda + k0+kb);
    }
    #pragma unroll
    for (int c=tid;c<BN*4;c+=256){
      int row=c>>2, kb=(c&3)*8;
      *(s16x8*)(Ws + row*BK + kb) = *(const s16x8*)(W + (n0+row)*ldw + k0+kb);
    }
    __syncthreads();
    bv8 af[FM], bf[FN];
    #pragma unroll
    for (int i=0;i<FM;i++) af[i] = ldf(As + (wr*(BM/2)+i*16+lr)*BK + lk);
    #pragma unroll
    for (int j=0;j<FN;j++) bf[j] = ldf(Ws + (wc*(BN/2)+j*16+lr)*BK + lk);
    #pragma unroll
    for (int i=0;i<FM;i++)
      #pragma unroll
      for (int j=0;j<FN;j++) acc[i][j] = mfma16(af[i], bf[j], acc[i][j]);
  }
  #pragma unroll
  for (int i=0;i<FM;i++)
    #pragma unroll
    for (int j=0;j<FN;j++)
      #pragma unroll
      for (int r=0;r<4;r++){
        int m = wr*(BM/2)+i*16+(lane>>4)*4+r;
        int n = wc*(BN/2)+j*16+lr;
        float v = acc[i][j][r];
        if (bias1) v += bias1[n0+n];
        if (bias2) v += bias2[n0+n];
        if (RELU) v = fmaxf(v,0.f);
        if (OUTF32) Cf[(m0+m)*ldc + n0+n] = v;
        else        Cb[(m0+m)*ldc + n0+n] = f2b(v);
      }
}

// ================= persistent encoder (r8 structure, sc1 exchange) =================
// grid 256: grp = bx&7 (dir*4+bt), kc = bx>>3 (16 cells)
struct EncP {
  const u16* xe; const int* lens;
  const u16 *Wihf,*Whhf,*Wihb,*Whhb;
  const float *bif,*bhf,*bib,*bhb;
  u16 *hf0,*hf1,*hb0,*hb1,*pooled;
  unsigned* flags;
};

__global__ __launch_bounds__(256,1) void enc_persist(EncP P){
  __shared__ __align__(16) u16 Wl[64*776];
  __shared__ __align__(16) u16 Hs[128*16];
  const int tid=threadIdx.x, lane=tid&63, w=tid>>6;
  const int bx=blockIdx.x;
  const int grp=bx&7, kc=bx>>3;
  const int dir=grp>>2, bt=grp&3;
  const int lr=lane&15, lk=(lane>>4)*8;
  unsigned* flags = P.flags + grp*2048;
  const u16* Wih = dir? P.Wihb : P.Wihf;
  const u16* Whh = dir? P.Whhb : P.Whhf;
  const float* bi = dir? P.bib : P.bif;
  const float* bh = dir? P.bhb : P.bhf;
  u16* h0 = dir? P.hb0 : P.hf0;
  u16* h1 = dir? P.hb1 : P.hf1;

  for (int idx=tid; idx<64*96; idx+=256){
    int row=idx/96, col=(idx%96)*8;
    int g=row>>4, c=row&15;
    size_t grow=(size_t)(g*512 + kc*16 + c);
    const u16* src = (col<256)? (Wih + grow*256 + col) : (Whh + grow*512 + (col-256));
    *(s16x8*)(Wl + row*776 + col) = *(const s16x8*)src;
  }
  const int cg = kc*16 + lr;
  const float b_i=bi[cg]+bh[cg], b_f=bi[512+cg]+bh[512+cg];
  const float b_g=bi[1024+cg]+bh[1024+cg], b_o=bi[1536+cg]+bh[1536+cg];
  const int r0 = w*32 + lr, r1i = r0 + 16;
  const int slen0 = P.lens[bt*128+r0], slen1 = P.lens[bt*128+r1i];
  const u16* xb0 = P.xe + (size_t)(bt*128+r0)*65536;
  const u16* xb1 = P.xe + (size_t)(bt*128+r1i)*65536;
  int elen[2][4]; float cs[2][4], hh[2][4], asum[2][4];
  #pragma unroll
  for (int i=0;i<2;i++)
    #pragma unroll
    for (int r=0;r<4;r++){
      int m=w*32+i*16+(lane>>4)*4+r;
      elen[i][r]=P.lens[bt*128+m];
      cs[i][r]=0.f; hh[i][r]=0.f; asum[i][r]=0.f;
    }
  __syncthreads();   // weights staged

  auto xpart=[&](int t_, f32x4 (&xacc)[2][4]){
    int tt0 = dir? max(slen0-1-t_,0) : t_;
    int tt1 = dir? max(slen1-1-t_,0) : t_;
    const u16* xr0 = xb0 + (size_t)tt0*256;
    const u16* xr1 = xb1 + (size_t)tt1*256;
    #pragma unroll
    for (int k=0;k<4;k++)
      #pragma unroll
      for (int kk=0;kk<2;kk++){
        bv8 a0 = ldf(xr0 + k*64 + kk*32 + lk);
        bv8 a1 = ldf(xr1 + k*64 + kk*32 + lk);
        #pragma unroll
        for (int g=0;g<4;g++){
          bv8 bf = ldf(Wl + (g*16+lr)*776 + k*64 + kk*32 + lk);
          xacc[0][g]=mfma16(a0,bf,xacc[0][g]);
          xacc[1][g]=mfma16(a1,bf,xacc[1][g]);
        }
      }
  };

  f32x4 xacc[2][4];
  #pragma unroll
  for (int i=0;i<2;i++)
    #pragma unroll
    for (int g=0;g<4;g++) xacc[i][g]=(f32x4){0.f,0.f,0.f,0.f};
  xpart(0, xacc);

  for (int t=0;t<256;t++){
    const u16* hp = (t&1)? h1 : h0;
    u16*       hn = (t&1)? h0 : h1;
    waitflags(flags, 0, 32, (unsigned)t);
    f32x4 acc[2][4];
    #pragma unroll
    for (int i=0;i<2;i++)
      #pragma unroll
      for (int g=0;g<4;g++) acc[i][g]=xacc[i][g];
    // h-part K=512: batched sc1 loads, depth-2 pipeline of 8-load batches
    {
      const u16* hr0 = hp + (size_t)(bt*128+r0)*512;
      const u16* hr1 = hp + (size_t)(bt*128+r1i)*512;
      s16x8 fb[2][8];
      auto issue=[&](int b, int k2){
        const u16* p0 = hr0 + k2*128;
        const u16* p1 = hr1 + k2*128;
        gld16(fb[b][0], p0+lk);    gld16(fb[b][1], p1+lk);
        gld16(fb[b][2], p0+32+lk); gld16(fb[b][3], p1+32+lk);
        gld16(fb[b][4], p0+64+lk); gld16(fb[b][5], p1+64+lk);
        gld16(fb[b][6], p0+96+lk); gld16(fb[b][7], p1+96+lk);
      };
      issue(0,0); issue(1,1);
      #pragma unroll
      for (int k2=0;k2<4;k2++){
        if (k2<3) wvm<8>(); else wvm<0>();
        const int b=k2&1;
        #pragma unroll
        for (int dk=0;dk<2;dk++)
          #pragma unroll
          for (int kk=0;kk<2;kk++){
            bv8 a0=cvt(fb[b][dk*4+kk*2]), a1=cvt(fb[b][dk*4+kk*2+1]);
            #pragma unroll
            for (int g=0;g<4;g++){
              bv8 bf=ldf(Wl + (g*16+lr)*776 + 256 + (2*k2+dk)*64 + kk*32 + lk);
              acc[0][g]=mfma16(a0,bf,acc[0][g]);
              acc[1][g]=mfma16(a1,bf,acc[1][g]);
            }
          }
        if (k2<2) issue(k2&1, k2+2);
      }
    }
    #pragma unroll
    for (int i=0;i<2;i++)
      #pragma unroll
      for (int r=0;r<4;r++){
        int m=w*32+i*16+(lane>>4)*4+r;
        if (t<elen[i][r]){
          float iv=sigm(acc[i][0][r]+b_i), fv=sigm(acc[i][1][r]+b_f);
          float gv=tanh_(acc[i][2][r]+b_g), ov=sigm(acc[i][3][r]+b_o);
          float c2=fv*cs[i][r]+iv*gv, h2v=ov*tanh_(c2);
          cs[i][r]=c2; hh[i][r]=h2v; asum[i][r]+=h2v;
        }
        Hs[m*16+lr]=f2b(hh[i][r]);
      }
    __syncthreads();
    #pragma unroll
    for (int q=0;q<2;q++){
      int cc=tid*2+q, sm=cc>>2, pt=cc&3;
      gst8(hn + (size_t)(bt*128+sm)*512 + kc*16 + pt*4, *(const u64*)(Hs + sm*16 + pt*4));
    }
    arrive(flags, kc, (unsigned)(t+1));
    // shadow: x-part for t+1
    #pragma unroll
    for (int i=0;i<2;i++)
      #pragma unroll
      for (int g=0;g<4;g++) xacc[i][g]=(f32x4){0.f,0.f,0.f,0.f};
    if (t<255) xpart(t+1, xacc);
  }
  #pragma unroll
  for (int i=0;i<2;i++)
    #pragma unroll
    for (int r=0;r<4;r++){
      int m=w*32+i*16+(lane>>4)*4+r;
      P.pooled[(size_t)(bt*128+m)*1024 + (size_t)dir*512 + cg]=f2b(asum[i][r]/(float)elen[i][r]);
    }
}

// ================= persistent decoder (r8 2-hop structure, sc1 exchange, batched loads) =================
// grid 256: grp=bx&7 (64 samples), kc=bx>>3. All blocks: G. kc<16: F1. kc in[16,24): F2+outd.
struct DecP {
  const u16 *Whhd, *Wcmp, *W1d, *W2d;
  const float *gix, *gp0, *pb, *b1d, *b2d;
  u16 *h0,*h1,*r1a,*r1b;
  float* outd;
  unsigned* flags;   // per group: [0..32) G flags, [32..48) F flags (x32 stride)
};

__global__ __launch_bounds__(256,1) void dec_persist(DecP P){
  __shared__ __align__(16) u16 Wh [64*520];
  __shared__ __align__(16) u16 WcL[64*264];
  __shared__ __align__(16) u16 F12[16*520];
  __shared__ __align__(16) u16 Hs[64*16];
  const int tid=threadIdx.x, lane=tid&63, w=tid>>6;
  const int bx=blockIdx.x;
  const int grp=bx&7, kc=bx>>3;
  const int g0 = grp*64;
  const int lr=lane&15, lk=(lane>>4)*8;
  unsigned* flags = P.flags + grp*2048;

  for (int idx=tid; idx<64*64; idx+=256){
    int row=idx>>6, col=(idx&63)*8;
    int g=row>>4, c=row&15;
    size_t grow=(size_t)(g*512+kc*16+c);
    *(s16x8*)(Wh + row*520 + col) = *(const s16x8*)(P.Whhd + grow*512 + col);
  }
  for (int idx=tid; idx<64*32; idx+=256){
    int row=idx>>5, col=(idx&31)*8;
    int g=row>>4, c=row&15;
    size_t grow=(size_t)(g*512+kc*16+c);
    *(s16x8*)(WcL + row*264 + col) = *(const s16x8*)(P.Wcmp + grow*256 + col);
  }
  if (kc<16){
    for (int idx=tid; idx<16*64; idx+=256){
      int rr=idx>>6, col=(idx&63)*8;
      *(s16x8*)(F12 + rr*520 + col) = *(const s16x8*)(P.W1d + (size_t)(kc*16+rr)*512 + col);
    }
  } else if (kc<24){
    for (int idx=tid; idx<16*32; idx+=256){
      int rr=idx>>5, col=(idx&31)*8;
      *(s16x8*)(F12 + rr*264 + col) = *(const s16x8*)(P.W2d + (size_t)((kc-16)*16+rr)*256 + col);
    }
  }
  float gx[4][4]; float pbr[4];
  #pragma unroll
  for (int g=0;g<4;g++)
    #pragma unroll
    for (int r=0;r<4;r++){
      int m=w*16+(lane>>4)*4+r;
      gx[g][r]=P.gix[(size_t)(g0+m)*2048 + (size_t)g*512 + kc*16 + lr];
    }
  #pragma unroll
  for (int g=0;g<4;g++) pbr[g] = P.pb[(size_t)g*512 + kc*16 + lr];
  const float b1=(kc<16)? P.b1d[kc*16+lr] : 0.f;
  const float b2=(kc>=16&&kc<24)? P.b2d[(kc-16)*16+lr] : 0.f;
  const int ar = w*16 + lr;
  float cs[4];
  f32x4 gh[4];
  #pragma unroll
  for (int r=0;r<4;r++) cs[r]=0.f;
  #pragma unroll
  for (int g=0;g<4;g++) gh[g]=(f32x4){0.f,0.f,0.f,0.f};
  __syncthreads();   // weights staged

  for (int t=0;t<256;t++){
    const u16* r1rd = (t&1)? P.r1b : P.r1a;
    u16* hn = (t&1)? P.h0 : P.h1;
    f32x4 acc[4];
    if (t==0){
      #pragma unroll
      for (int g=0;g<4;g++)
        #pragma unroll
        for (int r=0;r<4;r++){
          int m=w*16+(lane>>4)*4+r;
          acc[g][r] = gx[g][r] + P.gp0[(size_t)(g0+m)*2048 + (size_t)g*512 + kc*16 + lr];
        }
    } else {
      waitflags(flags, 32, 16, (unsigned)t);   // r1_t ready
      #pragma unroll
      for (int g=0;g<4;g++){
        acc[g] = (f32x4){gx[g][0]+pbr[g], gx[g][1]+pbr[g], gx[g][2]+pbr[g], gx[g][3]+pbr[g]};
        acc[g] = acc[g] + gh[g];
      }
      // Wcomp . r1_t (K=256): 8 sc1 loads, single drain
      const u16* rb = r1rd + (size_t)(g0+ar)*256;
      s16x8 fb[8];
      #pragma unroll
      for (int k=0;k<4;k++){
        gld16(fb[k*2],   rb + k*64 + lk);
        gld16(fb[k*2+1], rb + k*64 + 32 + lk);
      }
      wvm<0>();
      #pragma unroll
      for (int k=0;k<4;k++)
        #pragma unroll
        for (int kk=0;kk<2;kk++){
          bv8 a=cvt(fb[k*2+kk]);
          #pragma unroll
          for (int g=0;g<4;g++){
            bv8 bf=ldf(WcL + (g*16+lr)*264 + k*64 + kk*32 + lk);
            acc[g]=mfma16(a,bf,acc[g]);
          }
        }
    }
    // cell
    #pragma unroll
    for (int r=0;r<4;r++){
      float iv=sigm(acc[0][r]), fv=sigm(acc[1][r]);
      float gv=tanh_(acc[2][r]), ov=sigm(acc[3][r]);
      float c2=fv*cs[r]+iv*gv, h2v=ov*tanh_(c2);
      cs[r]=c2;
      int m=w*16+(lane>>4)*4+r;
      Hs[m*16+lr]=f2b(h2v);
    }
    __syncthreads();
    {
      int sm=tid>>2, pt=tid&3;
      gst8(hn + (size_t)(g0+sm)*512 + kc*16 + pt*4, *(const u64*)(Hs + sm*16 + pt*4));
    }
    arrive(flags, kc, (unsigned)(t+1));      // G flag
    // shadow: pose_t -> outd[t-1] (F2 blocks; r1_t already synced this step)
    if (kc>=16 && kc<24 && t>0){
      const u16* rb = r1rd + (size_t)(g0+ar)*256;
      f32x4 fa2=(f32x4){0.f,0.f,0.f,0.f};
      s16x8 fb[8];
      #pragma unroll
      for (int k=0;k<4;k++){
        gld16(fb[k*2],   rb + k*64 + lk);
        gld16(fb[k*2+1], rb + k*64 + 32 + lk);
      }
      wvm<0>();
      #pragma unroll
      for (int k=0;k<4;k++)
        #pragma unroll
        for (int kk=0;kk<2;kk++){
          bv8 a=cvt(fb[k*2+kk]);
          bv8 bf=ldf(F12 + lr*264 + k*64 + kk*32 + lk);
          fa2=mfma16(a,bf,fa2);
        }
      int pc=(kc-16)*16+lr;
      #pragma unroll
      for (int r=0;r<4;r++){
        int m=w*16+(lane>>4)*4+r;
        __builtin_nontemporal_store(fa2[r]+b2, P.outd + (size_t)(g0+m)*32768 + (size_t)(t-1)*128 + pc);
      }
    }
    waitflags(flags, 0, 32, (unsigned)(t+1));     // h_{t+1} ready
    // F: gh' = Whh.h_{t+1} (K=512, depth-2 batches of 8) + fused F1 (kc<16)
    f32x4 gn[4]; f32x4 fa=(f32x4){0.f,0.f,0.f,0.f};
    #pragma unroll
    for (int g=0;g<4;g++) gn[g]=(f32x4){0.f,0.f,0.f,0.f};
    {
      const u16* hb = hn + (size_t)(g0+ar)*512;
      s16x8 fb[2][8];
      auto issue=[&](int b, int h4){
        const u16* p = hb + h4*256;
        #pragma unroll
        for (int k=0;k<4;k++){
          gld16(fb[b][k*2],   p + k*64 + lk);
          gld16(fb[b][k*2+1], p + k*64 + 32 + lk);
        }
      };
      issue(0,0); issue(1,1);
      #pragma unroll
      for (int h4=0;h4<2;h4++){
        if (h4==0) wvm<8>(); else wvm<0>();
        #pragma unroll
        for (int k=0;k<4;k++)
          #pragma unroll
          for (int kk=0;kk<2;kk++){
            bv8 a=cvt(fb[h4][k*2+kk]);
            int col = h4*256 + k*64 + kk*32;
            #pragma unroll
            for (int g=0;g<4;g++){
              bv8 bf=ldf(Wh + (g*16+lr)*520 + col + lk);
              gn[g]=mfma16(a,bf,gn[g]);
            }
            if (kc<16){
              bv8 bf=ldf(F12 + lr*520 + col + lk);
              fa=mfma16(a,bf,fa);
            }
          }
      }
    }
    #pragma unroll
    for (int g=0;g<4;g++) gh[g]=gn[g];
    if (kc<16){
      u16* r1w = (t&1)? P.r1a : P.r1b;     // parity (t+1)&1
      #pragma unroll
      for (int r=0;r<4;r++){
        int m=w*16+(lane>>4)*4+r;
        Hs[m*16+lr]=f2b(fmaxf(fa[r]+b1,0.f));
      }
      __syncthreads();
      {
        int sm=tid>>2, pt=tid&3;
        gst8(r1w + (size_t)(g0+sm)*256 + kc*16 + pt*4, *(const u64*)(Hs + sm*16 + pt*4));
      }
      arrive(flags, 32+kc, (unsigned)(t+1));   // F flag
    }
  }
  // epilogue: pose_256 -> outd[255]
  if (kc>=16 && kc<24){
    waitflags(flags, 32, 16, 256u);
    const u16* rb = P.r1a + (size_t)(g0+ar)*256;  // r1_256 parity 0
    f32x4 fa2=(f32x4){0.f,0.f,0.f,0.f};
    s16x8 fb[8];
    #pragma unroll
    for (int k=0;k<4;k++){
      gld16(fb[k*2],   rb + k*64 + lk);
      gld16(fb[k*2+1], rb + k*64 + 32 + lk);
    }
    wvm<0>();
    #pragma unroll
    for (int k=0;k<4;k++)
      #pragma unroll
      for (int kk=0;kk<2;kk++){
        bv8 a=cvt(fb[k*2+kk]);
        bv8 bf=ldf(F12 + lr*264 + k*64 + kk*32 + lk);
        fa2=mfma16(a,bf,fa2);
      }
    int pc=(kc-16)*16+lr;
    #pragma unroll
    for (int r=0;r<4;r++){
      int m=w*16+(lane>>4)*4+r;
      __builtin_nontemporal_store(fa2[r]+b2, P.outd + (size_t)(g0+m)*32768 + (size_t)255*128 + pc);
    }
  }
}

__global__ __launch_bounds__(512) void len_cast(const int* __restrict__ lens, float* __restrict__ out){
  int i = threadIdx.x;
  if (i < 512) out[i] = (float)lens[i];
}

// ============================== host ==============================
extern "C" void kernel_launch(void* const* d_in, const int* in_sizes, int n_in,
                              void* d_out, int out_size, void* d_ws, size_t ws_size,
                              hipStream_t stream){
  (void)in_sizes; (void)n_in; (void)out_size; (void)ws_size;
  const float* x      = (const float*)d_in[0];
  const int*   lens   = (const int*)d_in[1];
  const float* ng     = (const float*)d_in[2];
  const float* nb     = (const float*)d_in[3];
  const float* We     = (const float*)d_in[4];
  const float* be     = (const float*)d_in[5];
  const float* Wih_f  = (const float*)d_in[6];
  const float* Whh_f  = (const float*)d_in[7];
  const float* bih_f  = (const float*)d_in[8];
  const float* bhh_f  = (const float*)d_in[9];
  const float* Wih_b  = (const float*)d_in[10];
  const float* Whh_b  = (const float*)d_in[11];
  const float* bih_b  = (const float*)d_in[12];
  const float* bhh_b  = (const float*)d_in[13];
  const float* W1e    = (const float*)d_in[14];
  const float* b1e    = (const float*)d_in[15];
  const float* W2e    = (const float*)d_in[16];
  const float* b2e    = (const float*)d_in[17];
  const float* Wd     = (const float*)d_in[18];
  const float* bd     = (const float*)d_in[19];
  const float* Wp1    = (const float*)d_in[20];
  const float* bp1    = (const float*)d_in[21];
  const float* Wp2    = (const float*)d_in[22];
  const float* bp2    = (const float*)d_in[23];
  const float* Wih_d  = (const float*)d_in[24];
  const float* Whh_d  = (const float*)d_in[25];
  const float* bih_d  = (const float*)d_in[26];
  const float* bhh_d  = (const float*)d_in[27];
  const float* W1d    = (const float*)d_in[28];
  const float* b1d    = (const float*)d_in[29];
  const float* W2d    = (const float*)d_in[30];
  const float* b2d    = (const float*)d_in[31];

  char* p = (char*)d_ws;
  auto carve = [&](size_t bytes)->void*{ void* r=(void*)p; p += (bytes+255)&~(size_t)255; return r; };
  float* mu   = (float*)carve(512*4);
  float* rstd = (float*)carve(512*4);
  u16* xe     = (u16*)carve((size_t)33554432*2);
  u16* wWe  = (u16*)carve(32768*2);
  u16* wIhf = (u16*)carve(524288*2);
  u16* wHhf = (u16*)carve(1048576*2);
  u16* wIhb = (u16*)carve(524288*2);
  u16* wHhb = (u16*)carve(1048576*2);
  u16* wW1e = (u16*)carve(524288*2);
  u16* wW2e = (u16*)carve(131072*2);
  u16* wWd  = (u16*)carve(65536*2);
  u16* wWp1 = (u16*)carve(65536*2);
  u16* wWp2 = (u16*)carve(32768*2);
  u16* wIhd = (u16*)carve(786432*2);
  u16* wHhd = (u16*)carve(1048576*2);
  u16* wW1d = (u16*)carve(131072*2);
  u16* wW2d = (u16*)carve(32768*2);
  u16* wW2dT  = (u16*)carve(32768*2);
  u16* wWcomp = (u16*)carve(524288*2);
  float* pbv  = (float*)carve(2048*4);
  float* gp0f = (float*)carve((size_t)1048576*4);
  u16* hf0  = (u16*)carve(524288);
  u16* hf1  = (u16*)carve(524288);
  u16* hb0  = (u16*)carve(524288);
  u16* hb1  = (u16*)carve(524288);
  u16* hd0  = (u16*)carve(524288);
  u16* hd1  = (u16*)carve(524288);
  u16* r1a  = (u16*)carve(262144);
  u16* r1b  = (u16*)carve(262144);
  u16* pooled = (u16*)carve(1048576);
  u16* out1   = (u16*)carve(524288);
  u16* zlat   = (u16*)carve(262144);
  u16* x0     = (u16*)carve(262144);
  u16* t0     = (u16*)carve(262144);
  float* gix  = (float*)carve(4194304);
  u16* pose   = (u16*)carve(131072);
  unsigned* barflags = (unsigned*)carve(16*2048*4);

  float* out_x   = (float*)d_out;
  float* out_dec = out_x + 16777216;
  float* out_len = out_x + 33554432;

  hipMemcpyAsync(out_x, x, (size_t)16777216*4, hipMemcpyDeviceToDevice, stream);
  hipMemsetAsync(hf0,0,524288,stream);
  hipMemsetAsync(hb0,0,524288,stream);
  hipMemsetAsync(barflags,0,16*2048*4,stream);

  CvtJobs J;
  const float* srcs[14] = {We,Wih_f,Whh_f,Wih_b,Whh_b,W1e,W2e,Wd,Wp1,Wp2,Wih_d,Whh_d,W1d,W2d};
  u16* dsts[14] = {wWe,wIhf,wHhf,wIhb,wHhb,wW1e,wW2e,wWd,wWp1,wWp2,wIhd,wHhd,wW1d,wW2d};
  int ns[14] = {32768,524288,1048576,524288,1048576,524288,131072,65536,65536,32768,786432,1048576,131072,32768};
  int blk=0;
  for (int i=0;i<14;i++){ J.s[i]=srcs[i]; J.d[i]=dsts[i]; J.start[i]=blk; blk += ns[i]/2048; }
  cvt_w<<<blk,256,0,stream>>>(J);

  tr_w2d<<<128,256,0,stream>>>(wW2d, wW2dT);
  pb_k<<<8,256,0,stream>>>(Wih_d, b2d, pbv);
  gemm_bt<64,64,false,false><<<dim3(4,32),256,0,stream>>>(wIhd+256,384, wW2dT,128, nullptr,nullptr, wWcomp,nullptr,256,128);

  ln_stats<<<512,256,0,stream>>>(x,mu,rstd);
  ln_gemm<<<dim3(2,1024),256,0,stream>>>(x,mu,rstd,ng,nb,wWe,be,xe);

  EncP EP = {xe,lens,wIhf,wHhf,wIhb,wHhb,bih_f,bhh_f,bih_b,bhh_b,hf0,hf1,hb0,hb1,pooled,barflags};
  {
    void* ea[] = {&EP};
    if (hipLaunchCooperativeKernel((void*)enc_persist, dim3(256), dim3(256), ea, 0, stream) != hipSuccess)
      enc_persist<<<256,256,0,stream>>>(EP);
  }

  gemm_bt<64,64,true ,false><<<dim3(8,8),256,0,stream>>>(pooled,1024,wW1e,1024,b1e,nullptr,out1,nullptr,512,1024);
  gemm_bt<64,64,false,false><<<dim3(4,8),256,0,stream>>>(out1,512,wW2e,512,b2e,nullptr,zlat,nullptr,256,512);
  gemm_bt<64,64,true ,false><<<dim3(4,8),256,0,stream>>>(zlat,256,wWd,256,bd,nullptr,x0,nullptr,256,256);
  gemm_bt<64,64,true ,false><<<dim3(4,8),256,0,stream>>>(x0,256,wWp1,256,bp1,nullptr,t0,nullptr,256,256);
  gemm_bt<64,64,false,false><<<dim3(2,8),256,0,stream>>>(t0,256,wWp2,256,bp2,nullptr,pose,nullptr,128,256);
  gemm_bt<64,128,false,true><<<dim3(16,8),256,0,stream>>>(x0,256,wIhd,384,bih_d,bhh_d,nullptr,gix,2048,256);
  gemm_bt<64,128,false,true><<<dim3(16,8),256,0,stream>>>(pose,128,wIhd+256,384,nullptr,nullptr,nullptr,gp0f,2048,128);

  DecP DP = {wHhd,wWcomp,wW1d,wW2d, gix,gp0f,pbv,b1d,b2d, hd0,hd1,r1a,r1b, out_dec, barflags + 8*2048};
  {
    void* da[] = {&DP};
    if (hipLaunchCooperativeKernel((void*)dec_persist, dim3(256), dim3(256), da, 0, stream) != hipSuccess)
      dec_persist<<<256,256,0,stream>>>(DP);
  }

  len_cast<<<1,512,0,stream>>>(lens,out_len);
}

// Round 12
// 4117.175 us; speedup vs baseline: 4.2501x; 1.0636x over previous
//
#include <hip/hip_runtime.h>
#include <stdint.h>
#include <math.h>

typedef unsigned short u16;
typedef unsigned long long u64;
typedef short s16x8 __attribute__((ext_vector_type(8)));
typedef __bf16 bv8 __attribute__((ext_vector_type(8)));
typedef float f32x4 __attribute__((ext_vector_type(4)));

#define DEV static __device__ __forceinline__

DEV float b2f(u16 x){ union{unsigned u; float f;} v; v.u=((unsigned)x)<<16; return v.f; }
DEV u16 f2b(float f){ union{float f; unsigned u;} v; v.f=f; unsigned u=v.u; u += 0x7fff + ((u>>16)&1u); return (u16)(u>>16); }
DEV float sigm(float x){ return 1.f/(1.f+__expf(-x)); }
DEV float tanh_(float x){ float cx=fminf(fmaxf(x,-20.f),20.f); float e=__expf(2.f*cx); return (e-1.f)/(e+1.f); }
DEV f32x4 mfma16(bv8 a, bv8 b, f32x4 c){ return __builtin_amdgcn_mfma_f32_16x16x32_bf16(a,b,c,0,0,0); }
DEV bv8 ldf(const u16* p){ return __builtin_bit_cast(bv8, *(const s16x8*)p); }
DEV bv8 cvt(const s16x8& v){ return __builtin_bit_cast(bv8, v); }

DEV unsigned ald4(const unsigned* p){ return __hip_atomic_load(p, __ATOMIC_RELAXED, __HIP_MEMORY_SCOPE_AGENT); }

// sc1 state exchange (r5/r11-proven): bypass L1+L2, coherent at L3. No fences anywhere.
DEV void gld16(s16x8& d, const u16* p){
  asm volatile("global_load_dwordx4 %0, %1, off sc0 sc1" : "=&v"(d) : "v"(p));
}
// plain cached asm load (read-only data; completion guaranteed by a later syncthreads/vmcnt0)
DEV void gldc16(s16x8& d, const u16* p){
  asm volatile("global_load_dwordx4 %0, %1, off" : "=&v"(d) : "v"(p));
}
DEV void gst8(u16* p, u64 v){
  asm volatile("global_store_dwordx2 %0, %1, off sc0 sc1" :: "v"(p), "v"(v) : "memory");
}
template<int N> DEV void wvm(){
  asm volatile("s_waitcnt vmcnt(%0)" :: "i"(N) : "memory");
  __builtin_amdgcn_sched_barrier(0);
}

// relaxed flag protocol: ordering = per-thread vmcnt(0) drain (sc1 stores reached L3) + block sync.
DEV void arrive(unsigned* flags, int my, unsigned e){
  asm volatile("s_waitcnt vmcnt(0)" ::: "memory");
  __syncthreads();
  if (threadIdx.x==0)
    __hip_atomic_store(&flags[my*32], e, __ATOMIC_RELAXED, __HIP_MEMORY_SCOPE_AGENT);
}
DEV void waitflags(unsigned* flags, int lo, int n, unsigned e){
  int t = (int)threadIdx.x;
  if (t>=lo && t<lo+n){
    unsigned v;
    do {
      asm volatile("global_load_dword %0, %1, off sc0 sc1\ns_waitcnt vmcnt(0)" : "=&v"(v) : "v"(flags + t*32) : "memory");
      if (v>=e) break;
      __builtin_amdgcn_s_sleep(1);
    } while (1);
  }
  __syncthreads();
}

// ---------------- weight f32 -> bf16 conversion ----------------
struct CvtJobs { const float* s[14]; u16* d[14]; int start[14]; };

__global__ __launch_bounds__(256) void cvt_w(CvtJobs J){
  int blk = blockIdx.x, tid = threadIdx.x;
  int j = 0;
  #pragma unroll
  for (int k=1;k<14;k++) if (blk >= J.start[k]) j = k;
  size_t idx = (size_t)(blk - J.start[j])*2048 + (size_t)tid*8;
  const f32x4* ps = (const f32x4*)(J.s[j] + idx);
  f32x4 a = ps[0], b = ps[1];
  s16x8 o;
  #pragma unroll
  for (int i=0;i<4;i++){ o[i]=(short)f2b(a[i]); o[4+i]=(short)f2b(b[i]); }
  *(s16x8*)(J.d[j] + idx) = o;
}

__global__ __launch_bounds__(256) void tr_w2d(const u16* __restrict__ in, u16* __restrict__ out){
  int idx = blockIdx.x*256 + threadIdx.x;  // 32768
  int r = idx>>7, p = idx&127;
  out[idx] = in[p*256 + r];
}

__global__ __launch_bounds__(256) void pb_k(const float* __restrict__ Wihd, const float* __restrict__ b2d,
                                            float* __restrict__ pb){
  int g = blockIdx.x*256 + threadIdx.x;    // 2048
  const float* row = Wihd + (size_t)g*384 + 256;
  float s = 0.f;
  for (int p=0;p<128;p++) s += row[p]*b2d[p];
  pb[g] = s;
}

// ---------------- LayerNorm stats ----------------
__global__ __launch_bounds__(256) void ln_stats(const float* __restrict__ x,
                                                float* __restrict__ mu, float* __restrict__ rstd){
  int b = blockIdx.x;
  const float* xb = x + (size_t)b*32768;
  float s1=0.f, s2=0.f;
  for (int i = threadIdx.x*4; i < 32768; i += 256*4){
    f32x4 v = *(const f32x4*)(xb+i);
    #pragma unroll
    for (int j=0;j<4;j++){ float f = v[j]; s1+=f; s2+=f*f; }
  }
  #pragma unroll
  for (int o=32;o>0;o>>=1){ s1 += __shfl_down(s1,o); s2 += __shfl_down(s2,o); }
  __shared__ float r1[4], r2[4];
  int w = threadIdx.x>>6;
  if ((threadIdx.x&63)==0){ r1[w]=s1; r2[w]=s2; }
  __syncthreads();
  if (threadIdx.x==0){
    float a=0.f,c=0.f;
    for (int i=0;i<4;i++){ a+=r1[i]; c+=r2[i]; }
    float m=a/32768.f, v=c/32768.f-m*m;
    mu[b]=m; rstd[b]=1.f/sqrtf(v+1e-5f);
  }
}

// ---------------- fused LN + encode GEMM ----------------
__global__ __launch_bounds__(256) void ln_gemm(const float* __restrict__ x,
    const float* __restrict__ mu, const float* __restrict__ rstd,
    const float* __restrict__ g, const float* __restrict__ bn,
    const u16* __restrict__ Wb, const float* __restrict__ be, u16* __restrict__ xe){
  __shared__ __align__(16) u16 As[128*32];
  __shared__ __align__(16) u16 Ws[128*32];
  int tid=threadIdx.x, lane=tid&63, wid=tid>>6;
  int wr=wid>>1, wc=wid&1;
  long m0=(long)blockIdx.y*128, n0=(long)blockIdx.x*128;
  int lr=lane&15, lk=(lane>>4)*8;
  f32x4 acc[4][4];
  #pragma unroll
  for (int i=0;i<4;i++)
    #pragma unroll
    for (int j=0;j<4;j++) acc[i][j]=(f32x4){0.f,0.f,0.f,0.f};

  for (int k0=0;k0<128;k0+=32){
    __syncthreads();
    #pragma unroll
    for (int c=tid;c<512;c+=256){
      int row=c>>2, kb=(c&3)*8;
      long R=m0+row;
      int b=(int)(R>>8), tt=(int)(R&255);
      float m=mu[b], rs=rstd[b];
      const f32x4* px=(const f32x4*)(x + R*128 + k0+kb);
      const f32x4* pg=(const f32x4*)(g + tt*128 + k0+kb);
      const f32x4* pb=(const f32x4*)(bn + tt*128 + k0+kb);
      f32x4 x0=px[0], x1=px[1], g0=pg[0], g1=pg[1], b0=pb[0], b1=pb[1];
      s16x8 o;
      #pragma unroll
      for (int j=0;j<4;j++){
        o[j]   = (short)f2b((x0[j]-m)*rs*g0[j] + b0[j]);
        o[4+j] = (short)f2b((x1[j]-m)*rs*g1[j] + b1[j]);
      }
      *(s16x8*)(As + row*32 + kb) = o;
    }
    #pragma unroll
    for (int c=tid;c<512;c+=256){
      int row=c>>2, kb=(c&3)*8;
      *(s16x8*)(Ws + row*32 + kb) = *(const s16x8*)(Wb + (n0+row)*128 + k0+kb);
    }
    __syncthreads();
    bv8 af[4], bf[4];
    #pragma unroll
    for (int i=0;i<4;i++) af[i] = ldf(As + (wr*64+i*16+lr)*32 + lk);
    #pragma unroll
    for (int j=0;j<4;j++) bf[j] = ldf(Ws + (wc*64+j*16+lr)*32 + lk);
    #pragma unroll
    for (int i=0;i<4;i++)
      #pragma unroll
      for (int j=0;j<4;j++) acc[i][j] = mfma16(af[i], bf[j], acc[i][j]);
  }
  #pragma unroll
  for (int i=0;i<4;i++)
    #pragma unroll
    for (int j=0;j<4;j++)
      #pragma unroll
      for (int r=0;r<4;r++){
        int m = wr*64+i*16+(lane>>4)*4+r;
        int n = wc*64+j*16+lr;
        float v = acc[i][j][r] + be[n0+n];
        xe[(m0+m)*256 + n0+n] = f2b(fmaxf(v,0.f));
      }
}

// ---------------- generic GEMM ----------------
template<int BM, int BN, bool RELU, bool OUTF32>
__global__ __launch_bounds__(256) void gemm_bt(const u16* __restrict__ A, int lda,
                                               const u16* __restrict__ W, int ldw,
                                               const float* __restrict__ bias1, const float* __restrict__ bias2,
                                               u16* __restrict__ Cb, float* __restrict__ Cf, int ldc, int K){
  constexpr int BK=32;
  constexpr int FM=BM/32, FN=BN/32;
  __shared__ __align__(16) u16 As[BM*BK];
  __shared__ __align__(16) u16 Ws[BN*BK];
  int tid=threadIdx.x, lane=tid&63, wid=tid>>6;
  int wr=wid>>1, wc=wid&1;
  long m0=(long)blockIdx.y*BM, n0=(long)blockIdx.x*BN;
  int lr=lane&15, lk=(lane>>4)*8;
  f32x4 acc[FM][FN];
  #pragma unroll
  for (int i=0;i<FM;i++)
    #pragma unroll
    for (int j=0;j<FN;j++) acc[i][j] = (f32x4){0.f,0.f,0.f,0.f};
  for (int k0=0;k0<K;k0+=BK){
    __syncthreads();
    #pragma unroll
    for (int c=tid;c<BM*4;c+=256){
      int row=c>>2, kb=(c&3)*8;
      *(s16x8*)(As + row*BK + kb) = *(const s16x8*)(A + (m0+row)*lda + k0+kb);
    }
    #pragma unroll
    for (int c=tid;c<BN*4;c+=256){
      int row=c>>2, kb=(c&3)*8;
      *(s16x8*)(Ws + row*BK + kb) = *(const s16x8*)(W + (n0+row)*ldw + k0+kb);
    }
    __syncthreads();
    bv8 af[FM], bf[FN];
    #pragma unroll
    for (int i=0;i<FM;i++) af[i] = ldf(As + (wr*(BM/2)+i*16+lr)*BK + lk);
    #pragma unroll
    for (int j=0;j<FN;j++) bf[j] = ldf(Ws + (wc*(BN/2)+j*16+lr)*BK + lk);
    #pragma unroll
    for (int i=0;i<FM;i++)
      #pragma unroll
      for (int j=0;j<FN;j++) acc[i][j] = mfma16(af[i], bf[j], acc[i][j]);
  }
  #pragma unroll
  for (int i=0;i<FM;i++)
    #pragma unroll
    for (int j=0;j<FN;j++)
      #pragma unroll
      for (int r=0;r<4;r++){
        int m = wr*(BM/2)+i*16+(lane>>4)*4+r;
        int n = wc*(BN/2)+j*16+lr;
        float v = acc[i][j][r];
        if (bias1) v += bias1[n0+n];
        if (bias2) v += bias2[n0+n];
        if (RELU) v = fmaxf(v,0.f);
        if (OUTF32) Cf[(m0+m)*ldc + n0+n] = v;
        else        Cb[(m0+m)*ldc + n0+n] = f2b(v);
      }
}

// ================= persistent encoder (512 threads, 8 waves x 16 samples) =================
// grid 256: grp = bx&7 (dir*4+bt), kc = bx>>3 (16 cells)
struct EncP {
  const u16* xe; const int* lens;
  const u16 *Wihf,*Whhf,*Wihb,*Whhb;
  const float *bif,*bhf,*bib,*bhb;
  u16 *hf0,*hf1,*hb0,*hb1,*pooled;
  unsigned* flags;
};

__global__ __launch_bounds__(512,1) void enc_persist(EncP P){
  __shared__ __align__(16) u16 Wl[64*776];
  __shared__ __align__(16) u16 Hs[128*16];
  const int tid=threadIdx.x, lane=tid&63, w=tid>>6;   // w in 0..7
  const int bx=blockIdx.x;
  const int grp=bx&7, kc=bx>>3;
  const int dir=grp>>2, bt=grp&3;
  const int lr=lane&15, lk=(lane>>4)*8;
  unsigned* flags = P.flags + grp*2048;
  const u16* Wih = dir? P.Wihb : P.Wihf;
  const u16* Whh = dir? P.Whhb : P.Whhf;
  const float* bi = dir? P.bib : P.bif;
  const float* bh = dir? P.bhb : P.bhf;
  u16* h0 = dir? P.hb0 : P.hf0;
  u16* h1 = dir? P.hb1 : P.hf1;

  for (int idx=tid; idx<64*96; idx+=512){
    int row=idx/96, col=(idx%96)*8;
    int g=row>>4, c=row&15;
    size_t grow=(size_t)(g*512 + kc*16 + c);
    const u16* src = (col<256)? (Wih + grow*256 + col) : (Whh + grow*512 + (col-256));
    *(s16x8*)(Wl + row*776 + col) = *(const s16x8*)src;
  }
  const int cg = kc*16 + lr;
  const float b_i=bi[cg]+bh[cg], b_f=bi[512+cg]+bh[512+cg];
  const float b_g=bi[1024+cg]+bh[1024+cg], b_o=bi[1536+cg]+bh[1536+cg];
  const int r0 = w*16 + lr;                       // this lane's sample row (wave owns 16)
  const int slen0 = P.lens[bt*128+r0];
  const u16* xb0 = P.xe + (size_t)(bt*128+r0)*65536;
  int elen[4]; float cs[4], hh[4], asum[4];
  #pragma unroll
  for (int r=0;r<4;r++){
    int m=w*16+(lane>>4)*4+r;
    elen[r]=P.lens[bt*128+m];
    cs[r]=0.f; hh[r]=0.f; asum[r]=0.f;
  }
  __syncthreads();   // weights staged

  // x-fragment prefetch registers (consumed next step, completion via waitflags' sync)
  s16x8 rx[8];
  auto issue_rx=[&](int t_){
    int tt = dir? max(slen0-1-t_,0) : t_;
    const u16* xr = xb0 + (size_t)tt*256;
    #pragma unroll
    for (int j=0;j<8;j++) gldc16(rx[j], xr + j*32 + lk);
  };
  issue_rx(0);

  for (int t=0;t<256;t++){
    const u16* hp = (t&1)? h1 : h0;
    u16*       hn = (t&1)? h0 : h1;
    waitflags(flags, 0, 32, (unsigned)t);     // also guarantees rx complete (vmcnt0 in poll/sync)
    // issue all 16 h-loads (sc1, counted), then x-part MFMAs from registers under their latency
    s16x8 fb[16];
    {
      const u16* hr = hp + (size_t)(bt*128+r0)*512;
      #pragma unroll
      for (int j=0;j<16;j++) gld16(fb[j], hr + j*32 + lk);
    }
    f32x4 acc[4];
    #pragma unroll
    for (int g=0;g<4;g++) acc[g]=(f32x4){0.f,0.f,0.f,0.f};
    #pragma unroll
    for (int j=0;j<8;j++){
      bv8 a = cvt(rx[j]);
      #pragma unroll
      for (int g=0;g<4;g++){
        bv8 bf = ldf(Wl + (g*16+lr)*776 + j*32 + lk);
        acc[g]=mfma16(a,bf,acc[g]);
      }
    }
    // h-part: progressive drain
    wvm<8>();
    #pragma unroll
    for (int j=0;j<8;j++){
      bv8 a = cvt(fb[j]);
      #pragma unroll
      for (int g=0;g<4;g++){
        bv8 bf = ldf(Wl + (g*16+lr)*776 + 256 + j*32 + lk);
        acc[g]=mfma16(a,bf,acc[g]);
      }
    }
    wvm<0>();
    #pragma unroll
    for (int j=8;j<16;j++){
      bv8 a = cvt(fb[j]);
      #pragma unroll
      for (int g=0;g<4;g++){
        bv8 bf = ldf(Wl + (g*16+lr)*776 + 256 + j*32 + lk);
        acc[g]=mfma16(a,bf,acc[g]);
      }
    }
    // cell
    #pragma unroll
    for (int r=0;r<4;r++){
      int m=w*16+(lane>>4)*4+r;
      if (t<elen[r]){
        float iv=sigm(acc[0][r]+b_i), fv=sigm(acc[1][r]+b_f);
        float gv=tanh_(acc[2][r]+b_g), ov=sigm(acc[3][r]+b_o);
        float c2=fv*cs[r]+iv*gv, h2v=ov*tanh_(c2);
        cs[r]=c2; hh[r]=h2v; asum[r]+=h2v;
      }
      Hs[m*16+lr]=f2b(hh[r]);
    }
    __syncthreads();
    {
      int sm=tid>>2, pt=tid&3;   // 512 threads: 128 samples x 4 chunks of 8B
      gst8(hn + (size_t)(bt*128+sm)*512 + kc*16 + pt*4, *(const u64*)(Hs + sm*16 + pt*4));
    }
    arrive(flags, kc, (unsigned)(t+1));
    if (t<255) issue_rx(t+1);
  }
  #pragma unroll
  for (int r=0;r<4;r++){
    int m=w*16+(lane>>4)*4+r;
    P.pooled[(size_t)(bt*128+m)*1024 + (size_t)dir*512 + cg]=f2b(asum[r]/(float)elen[r]);
  }
}

// ================= persistent decoder (r11-proven, unchanged) =================
// grid 256: grp=bx&7 (64 samples), kc=bx>>3. All blocks: G. kc<16: F1. kc in[16,24): F2+outd.
struct DecP {
  const u16 *Whhd, *Wcmp, *W1d, *W2d;
  const float *gix, *gp0, *pb, *b1d, *b2d;
  u16 *h0,*h1,*r1a,*r1b;
  float* outd;
  unsigned* flags;   // per group: [0..32) G flags, [32..48) F flags (x32 stride)
};

__global__ __launch_bounds__(256,1) void dec_persist(DecP P){
  __shared__ __align__(16) u16 Wh [64*520];
  __shared__ __align__(16) u16 WcL[64*264];
  __shared__ __align__(16) u16 F12[16*520];
  __shared__ __align__(16) u16 Hs[64*16];
  const int tid=threadIdx.x, lane=tid&63, w=tid>>6;
  const int bx=blockIdx.x;
  const int grp=bx&7, kc=bx>>3;
  const int g0 = grp*64;
  const int lr=lane&15, lk=(lane>>4)*8;
  unsigned* flags = P.flags + grp*2048;

  for (int idx=tid; idx<64*64; idx+=256){
    int row=idx>>6, col=(idx&63)*8;
    int g=row>>4, c=row&15;
    size_t grow=(size_t)(g*512+kc*16+c);
    *(s16x8*)(Wh + row*520 + col) = *(const s16x8*)(P.Whhd + grow*512 + col);
  }
  for (int idx=tid; idx<64*32; idx+=256){
    int row=idx>>5, col=(idx&31)*8;
    int g=row>>4, c=row&15;
    size_t grow=(size_t)(g*512+kc*16+c);
    *(s16x8*)(WcL + row*264 + col) = *(const s16x8*)(P.Wcmp + grow*256 + col);
  }
  if (kc<16){
    for (int idx=tid; idx<16*64; idx+=256){
      int rr=idx>>6, col=(idx&63)*8;
      *(s16x8*)(F12 + rr*520 + col) = *(const s16x8*)(P.W1d + (size_t)(kc*16+rr)*512 + col);
    }
  } else if (kc<24){
    for (int idx=tid; idx<16*32; idx+=256){
      int rr=idx>>5, col=(idx&31)*8;
      *(s16x8*)(F12 + rr*264 + col) = *(const s16x8*)(P.W2d + (size_t)((kc-16)*16+rr)*256 + col);
    }
  }
  float gx[4][4]; float pbr[4];
  #pragma unroll
  for (int g=0;g<4;g++)
    #pragma unroll
    for (int r=0;r<4;r++){
      int m=w*16+(lane>>4)*4+r;
      gx[g][r]=P.gix[(size_t)(g0+m)*2048 + (size_t)g*512 + kc*16 + lr];
    }
  #pragma unroll
  for (int g=0;g<4;g++) pbr[g] = P.pb[(size_t)g*512 + kc*16 + lr];
  const float b1=(kc<16)? P.b1d[kc*16+lr] : 0.f;
  const float b2=(kc>=16&&kc<24)? P.b2d[(kc-16)*16+lr] : 0.f;
  const int ar = w*16 + lr;
  float cs[4];
  f32x4 gh[4];
  #pragma unroll
  for (int r=0;r<4;r++) cs[r]=0.f;
  #pragma unroll
  for (int g=0;g<4;g++) gh[g]=(f32x4){0.f,0.f,0.f,0.f};
  __syncthreads();   // weights staged

  for (int t=0;t<256;t++){
    const u16* r1rd = (t&1)? P.r1b : P.r1a;
    u16* hn = (t&1)? P.h0 : P.h1;
    f32x4 acc[4];
    if (t==0){
      #pragma unroll
      for (int g=0;g<4;g++)
        #pragma unroll
        for (int r=0;r<4;r++){
          int m=w*16+(lane>>4)*4+r;
          acc[g][r] = gx[g][r] + P.gp0[(size_t)(g0+m)*2048 + (size_t)g*512 + kc*16 + lr];
        }
    } else {
      waitflags(flags, 32, 16, (unsigned)t);   // r1_t ready
      #pragma unroll
      for (int g=0;g<4;g++){
        acc[g] = (f32x4){gx[g][0]+pbr[g], gx[g][1]+pbr[g], gx[g][2]+pbr[g], gx[g][3]+pbr[g]};
        acc[g] = acc[g] + gh[g];
      }
      const u16* rb = r1rd + (size_t)(g0+ar)*256;
      s16x8 fb[8];
      #pragma unroll
      for (int k=0;k<4;k++){
        gld16(fb[k*2],   rb + k*64 + lk);
        gld16(fb[k*2+1], rb + k*64 + 32 + lk);
      }
      wvm<0>();
      #pragma unroll
      for (int k=0;k<4;k++)
        #pragma unroll
        for (int kk=0;kk<2;kk++){
          bv8 a=cvt(fb[k*2+kk]);
          #pragma unroll
          for (int g=0;g<4;g++){
            bv8 bf=ldf(WcL + (g*16+lr)*264 + k*64 + kk*32 + lk);
            acc[g]=mfma16(a,bf,acc[g]);
          }
        }
    }
    // cell
    #pragma unroll
    for (int r=0;r<4;r++){
      float iv=sigm(acc[0][r]), fv=sigm(acc[1][r]);
      float gv=tanh_(acc[2][r]), ov=sigm(acc[3][r]);
      float c2=fv*cs[r]+iv*gv, h2v=ov*tanh_(c2);
      cs[r]=c2;
      int m=w*16+(lane>>4)*4+r;
      Hs[m*16+lr]=f2b(h2v);
    }
    __syncthreads();
    {
      int sm=tid>>2, pt=tid&3;
      gst8(hn + (size_t)(g0+sm)*512 + kc*16 + pt*4, *(const u64*)(Hs + sm*16 + pt*4));
    }
    arrive(flags, kc, (unsigned)(t+1));      // G flag
    if (kc>=16 && kc<24 && t>0){
      const u16* rb = r1rd + (size_t)(g0+ar)*256;
      f32x4 fa2=(f32x4){0.f,0.f,0.f,0.f};
      s16x8 fb[8];
      #pragma unroll
      for (int k=0;k<4;k++){
        gld16(fb[k*2],   rb + k*64 + lk);
        gld16(fb[k*2+1], rb + k*64 + 32 + lk);
      }
      wvm<0>();
      #pragma unroll
      for (int k=0;k<4;k++)
        #pragma unroll
        for (int kk=0;kk<2;kk++){
          bv8 a=cvt(fb[k*2+kk]);
          bv8 bf=ldf(F12 + lr*264 + k*64 + kk*32 + lk);
          fa2=mfma16(a,bf,fa2);
        }
      int pc=(kc-16)*16+lr;
      #pragma unroll
      for (int r=0;r<4;r++){
        int m=w*16+(lane>>4)*4+r;
        __builtin_nontemporal_store(fa2[r]+b2, P.outd + (size_t)(g0+m)*32768 + (size_t)(t-1)*128 + pc);
      }
    }
    waitflags(flags, 0, 32, (unsigned)(t+1));     // h_{t+1} ready
    f32x4 gn[4]; f32x4 fa=(f32x4){0.f,0.f,0.f,0.f};
    #pragma unroll
    for (int g=0;g<4;g++) gn[g]=(f32x4){0.f,0.f,0.f,0.f};
    {
      const u16* hb = hn + (size_t)(g0+ar)*512;
      s16x8 fb[2][8];
      auto issue=[&](int b, int h4){
        const u16* p = hb + h4*256;
        #pragma unroll
        for (int k=0;k<4;k++){
          gld16(fb[b][k*2],   p + k*64 + lk);
          gld16(fb[b][k*2+1], p + k*64 + 32 + lk);
        }
      };
      issue(0,0); issue(1,1);
      #pragma unroll
      for (int h4=0;h4<2;h4++){
        if (h4==0) wvm<8>(); else wvm<0>();
        #pragma unroll
        for (int k=0;k<4;k++)
          #pragma unroll
          for (int kk=0;kk<2;kk++){
            bv8 a=cvt(fb[h4][k*2+kk]);
            int col = h4*256 + k*64 + kk*32;
            #pragma unroll
            for (int g=0;g<4;g++){
              bv8 bf=ldf(Wh + (g*16+lr)*520 + col + lk);
              gn[g]=mfma16(a,bf,gn[g]);
            }
            if (kc<16){
              bv8 bf=ldf(F12 + lr*520 + col + lk);
              fa=mfma16(a,bf,fa);
            }
          }
      }
    }
    #pragma unroll
    for (int g=0;g<4;g++) gh[g]=gn[g];
    if (kc<16){
      u16* r1w = (t&1)? P.r1a : P.r1b;     // parity (t+1)&1
      #pragma unroll
      for (int r=0;r<4;r++){
        int m=w*16+(lane>>4)*4+r;
        Hs[m*16+lr]=f2b(fmaxf(fa[r]+b1,0.f));
      }
      __syncthreads();
      {
        int sm=tid>>2, pt=tid&3;
        gst8(r1w + (size_t)(g0+sm)*256 + kc*16 + pt*4, *(const u64*)(Hs + sm*16 + pt*4));
      }
      arrive(flags, 32+kc, (unsigned)(t+1));   // F flag
    }
  }
  // epilogue: pose_256 -> outd[255]
  if (kc>=16 && kc<24){
    waitflags(flags, 32, 16, 256u);
    const u16* rb = P.r1a + (size_t)(g0+ar)*256;  // r1_256 parity 0
    f32x4 fa2=(f32x4){0.f,0.f,0.f,0.f};
    s16x8 fb[8];
    #pragma unroll
    for (int k=0;k<4;k++){
      gld16(fb[k*2],   rb + k*64 + lk);
      gld16(fb[k*2+1], rb + k*64 + 32 + lk);
    }
    wvm<0>();
    #pragma unroll
    for (int k=0;k<4;k++)
      #pragma unroll
      for (int kk=0;kk<2;kk++){
        bv8 a=cvt(fb[k*2+kk]);
        bv8 bf=ldf(F12 + lr*264 + k*64 + kk*32 + lk);
        fa2=mfma16(a,bf,fa2);
      }
    int pc=(kc-16)*16+lr;
    #pragma unroll
    for (int r=0;r<4;r++){
      int m=w*16+(lane>>4)*4+r;
      __builtin_nontemporal_store(fa2[r]+b2, P.outd + (size_t)(g0+m)*32768 + (size_t)255*128 + pc);
    }
  }
}

__global__ __launch_bounds__(512) void len_cast(const int* __restrict__ lens, float* __restrict__ out){
  int i = threadIdx.x;
  if (i < 512) out[i] = (float)lens[i];
}

// ============================== host ==============================
extern "C" void kernel_launch(void* const* d_in, const int* in_sizes, int n_in,
                              void* d_out, int out_size, void* d_ws, size_t ws_size,
                              hipStream_t stream){
  (void)in_sizes; (void)n_in; (void)out_size; (void)ws_size;
  const float* x      = (const float*)d_in[0];
  const int*   lens   = (const int*)d_in[1];
  const float* ng     = (const float*)d_in[2];
  const float* nb     = (const float*)d_in[3];
  const float* We     = (const float*)d_in[4];
  const float* be     = (const float*)d_in[5];
  const float* Wih_f  = (const float*)d_in[6];
  const float* Whh_f  = (const float*)d_in[7];
  const float* bih_f  = (const float*)d_in[8];
  const float* bhh_f  = (const float*)d_in[9];
  const float* Wih_b  = (const float*)d_in[10];
  const float* Whh_b  = (const float*)d_in[11];
  const float* bih_b  = (const float*)d_in[12];
  const float* bhh_b  = (const float*)d_in[13];
  const float* W1e    = (const float*)d_in[14];
  const float* b1e    = (const float*)d_in[15];
  const float* W2e    = (const float*)d_in[16];
  const float* b2e    = (const float*)d_in[17];
  const float* Wd     = (const float*)d_in[18];
  const float* bd     = (const float*)d_in[19];
  const float* Wp1    = (const float*)d_in[20];
  const float* bp1    = (const float*)d_in[21];
  const float* Wp2    = (const float*)d_in[22];
  const float* bp2    = (const float*)d_in[23];
  const float* Wih_d  = (const float*)d_in[24];
  const float* Whh_d  = (const float*)d_in[25];
  const float* bih_d  = (const float*)d_in[26];
  const float* bhh_d  = (const float*)d_in[27];
  const float* W1d    = (const float*)d_in[28];
  const float* b1d    = (const float*)d_in[29];
  const float* W2d    = (const float*)d_in[30];
  const float* b2d    = (const float*)d_in[31];

  char* p = (char*)d_ws;
  auto carve = [&](size_t bytes)->void*{ void* r=(void*)p; p += (bytes+255)&~(size_t)255; return r; };
  float* mu   = (float*)carve(512*4);
  float* rstd = (float*)carve(512*4);
  u16* xe     = (u16*)carve((size_t)33554432*2);
  u16* wWe  = (u16*)carve(32768*2);
  u16* wIhf = (u16*)carve(524288*2);
  u16* wHhf = (u16*)carve(1048576*2);
  u16* wIhb = (u16*)carve(524288*2);
  u16* wHhb = (u16*)carve(1048576*2);
  u16* wW1e = (u16*)carve(524288*2);
  u16* wW2e = (u16*)carve(131072*2);
  u16* wWd  = (u16*)carve(65536*2);
  u16* wWp1 = (u16*)carve(65536*2);
  u16* wWp2 = (u16*)carve(32768*2);
  u16* wIhd = (u16*)carve(786432*2);
  u16* wHhd = (u16*)carve(1048576*2);
  u16* wW1d = (u16*)carve(131072*2);
  u16* wW2d = (u16*)carve(32768*2);
  u16* wW2dT  = (u16*)carve(32768*2);
  u16* wWcomp = (u16*)carve(524288*2);
  float* pbv  = (float*)carve(2048*4);
  float* gp0f = (float*)carve((size_t)1048576*4);
  u16* hf0  = (u16*)carve(524288);
  u16* hf1  = (u16*)carve(524288);
  u16* hb0  = (u16*)carve(524288);
  u16* hb1  = (u16*)carve(524288);
  u16* hd0  = (u16*)carve(524288);
  u16* hd1  = (u16*)carve(524288);
  u16* r1a  = (u16*)carve(262144);
  u16* r1b  = (u16*)carve(262144);
  u16* pooled = (u16*)carve(1048576);
  u16* out1   = (u16*)carve(524288);
  u16* zlat   = (u16*)carve(262144);
  u16* x0     = (u16*)carve(262144);
  u16* t0     = (u16*)carve(262144);
  float* gix  = (float*)carve(4194304);
  u16* pose   = (u16*)carve(131072);
  unsigned* barflags = (unsigned*)carve(16*2048*4);

  float* out_x   = (float*)d_out;
  float* out_dec = out_x + 16777216;
  float* out_len = out_x + 33554432;

  hipMemcpyAsync(out_x, x, (size_t)16777216*4, hipMemcpyDeviceToDevice, stream);
  hipMemsetAsync(hf0,0,524288,stream);
  hipMemsetAsync(hb0,0,524288,stream);
  hipMemsetAsync(barflags,0,16*2048*4,stream);

  CvtJobs J;
  const float* srcs[14] = {We,Wih_f,Whh_f,Wih_b,Whh_b,W1e,W2e,Wd,Wp1,Wp2,Wih_d,Whh_d,W1d,W2d};
  u16* dsts[14] = {wWe,wIhf,wHhf,wIhb,wHhb,wW1e,wW2e,wWd,wWp1,wWp2,wIhd,wHhd,wW1d,wW2d};
  int ns[14] = {32768,524288,1048576,524288,1048576,524288,131072,65536,65536,32768,786432,1048576,131072,32768};
  int blk=0;
  for (int i=0;i<14;i++){ J.s[i]=srcs[i]; J.d[i]=dsts[i]; J.start[i]=blk; blk += ns[i]/2048; }
  cvt_w<<<blk,256,0,stream>>>(J);

  tr_w2d<<<128,256,0,stream>>>(wW2d, wW2dT);
  pb_k<<<8,256,0,stream>>>(Wih_d, b2d, pbv);
  gemm_bt<64,64,false,false><<<dim3(4,32),256,0,stream>>>(wIhd+256,384, wW2dT,128, nullptr,nullptr, wWcomp,nullptr,256,128);

  ln_stats<<<512,256,0,stream>>>(x,mu,rstd);
  ln_gemm<<<dim3(2,1024),256,0,stream>>>(x,mu,rstd,ng,nb,wWe,be,xe);

  EncP EP = {xe,lens,wIhf,wHhf,wIhb,wHhb,bih_f,bhh_f,bih_b,bhh_b,hf0,hf1,hb0,hb1,pooled,barflags};
  {
    void* ea[] = {&EP};
    if (hipLaunchCooperativeKernel((void*)enc_persist, dim3(256), dim3(512), ea, 0, stream) != hipSuccess)
      enc_persist<<<256,512,0,stream>>>(EP);
  }

  gemm_bt<64,64,true ,false><<<dim3(8,8),256,0,stream>>>(pooled,1024,wW1e,1024,b1e,nullptr,out1,nullptr,512,1024);
  gemm_bt<64,64,false,false><<<dim3(4,8),256,0,stream>>>(out1,512,wW2e,512,b2e,nullptr,zlat,nullptr,256,512);
  gemm_bt<64,64,true ,false><<<dim3(4,8),256,0,stream>>>(zlat,256,wWd,256,bd,nullptr,x0,nullptr,256,256);
  gemm_bt<64,64,true ,false><<<dim3(4,8),256,0,stream>>>(x0,256,wWp1,256,bp1,nullptr,t0,nullptr,256,256);
  gemm_bt<64,64,false,false><<<dim3(2,8),256,0,stream>>>(t0,256,wWp2,256,bp2,nullptr,pose,nullptr,128,256);
  gemm_bt<64,128,false,true><<<dim3(16,8),256,0,stream>>>(x0,256,wIhd,384,bih_d,bhh_d,nullptr,gix,2048,256);
  gemm_bt<64,128,false,true><<<dim3(16,8),256,0,stream>>>(pose,128,wIhd+256,384,nullptr,nullptr,nullptr,gp0f,2048,128);

  DecP DP = {wHhd,wWcomp,wW1d,wW2d, gix,gp0f,pbv,b1d,b2d, hd0,hd1,r1a,r1b, out_dec, barflags + 8*2048};
  {
    void* da[] = {&DP};
    if (hipLaunchCooperativeKernel((void*)dec_persist, dim3(256), dim3(256), da, 0, stream) != hipSuccess)
      dec_persist<<<256,256,0,stream>>>(DP);
  }

  len_cast<<<1,512,0,stream>>>(lens,out_len);
}

// Round 13
// 3979.644 us; speedup vs baseline: 4.3970x; 1.0346x over previous
//
#include <hip/hip_runtime.h>
#include <stdint.h>
#include <math.h>

typedef unsigned short u16;
typedef unsigned char u8;
typedef unsigned u32;
typedef unsigned long long u64;
typedef short s16x8 __attribute__((ext_vector_type(8)));
typedef int i32x2 __attribute__((ext_vector_type(2)));
typedef __bf16 bv8 __attribute__((ext_vector_type(8)));
typedef float f32x4 __attribute__((ext_vector_type(4)));

#define DEV static __device__ __forceinline__

DEV float b2f(u16 x){ union{unsigned u; float f;} v; v.u=((unsigned)x)<<16; return v.f; }
DEV u16 f2b(float f){ union{float f; unsigned u;} v; v.f=f; unsigned u=v.u; u += 0x7fff + ((u>>16)&1u); return (u16)(u>>16); }
DEV float sigm(float x){ return 1.f/(1.f+__expf(-x)); }
DEV float tanh_(float x){ float cx=fminf(fmaxf(x,-20.f),20.f); float e=__expf(2.f*cx); return (e-1.f)/(e+1.f); }
DEV f32x4 mfma16(bv8 a, bv8 b, f32x4 c){ return __builtin_amdgcn_mfma_f32_16x16x32_bf16(a,b,c,0,0,0); }
DEV f32x4 mfma8(u64 a, u64 b, f32x4 c){ return __builtin_amdgcn_mfma_f32_16x16x32_fp8_fp8((long)a,(long)b,c,0,0,0); }
DEV bv8 ldf(const u16* p){ return __builtin_bit_cast(bv8, *(const s16x8*)p); }
DEV bv8 cvt(const s16x8& v){ return __builtin_bit_cast(bv8, v); }
DEV u8 f2e4(float f){ return (u8)__builtin_amdgcn_cvt_pk_fp8_f32(f, f, 0, false); }

DEV unsigned ald4(const unsigned* p){ return __hip_atomic_load(p, __ATOMIC_RELAXED, __HIP_MEMORY_SCOPE_AGENT); }

// sc1 state exchange (r5/r11-proven): bypass L1+L2, coherent at L3. No fences anywhere.
DEV void gld16(s16x8& d, const u16* p){
  asm volatile("global_load_dwordx4 %0, %1, off sc0 sc1" : "=&v"(d) : "v"(p));
}
DEV void gld8(u64& d, const u8* p){
  asm volatile("global_load_dwordx2 %0, %1, off sc0 sc1" : "=&v"(d) : "v"(p));
}
DEV void gldc8(u64& d, const u8* p){
  asm volatile("global_load_dwordx2 %0, %1, off" : "=&v"(d) : "v"(p));
}
DEV void gst8(u16* p, u64 v){
  asm volatile("global_store_dwordx2 %0, %1, off sc0 sc1" :: "v"(p), "v"(v) : "memory");
}
DEV void gst4(u8* p, u32 v){
  asm volatile("global_store_dword %0, %1, off sc0 sc1" :: "v"(p), "v"(v) : "memory");
}
template<int N> DEV void wvm(){
  asm volatile("s_waitcnt vmcnt(%0)" :: "i"(N) : "memory");
  __builtin_amdgcn_sched_barrier(0);
}

// relaxed flag protocol: ordering = per-thread vmcnt(0) drain (sc1 stores reached L3) + block sync.
DEV void arrive(unsigned* flags, int my, unsigned e){
  asm volatile("s_waitcnt vmcnt(0)" ::: "memory");
  __syncthreads();
  if (threadIdx.x==0)
    __hip_atomic_store(&flags[my*32], e, __ATOMIC_RELAXED, __HIP_MEMORY_SCOPE_AGENT);
}
DEV void waitflags(unsigned* flags, int lo, int n, unsigned e){
  int t = (int)threadIdx.x;
  if (t>=lo && t<lo+n){
    unsigned v;
    do {
      asm volatile("global_load_dword %0, %1, off sc0 sc1\ns_waitcnt vmcnt(0)" : "=&v"(v) : "v"(flags + t*32) : "memory");
      if (v>=e) break;
      __builtin_amdgcn_s_sleep(1);
    } while (1);
  }
  __syncthreads();
}

// ---------------- weight f32 -> bf16 conversion ----------------
struct CvtJobs { const float* s[14]; u16* d[14]; int start[14]; };

__global__ __launch_bounds__(256) void cvt_w(CvtJobs J){
  int blk = blockIdx.x, tid = threadIdx.x;
  int j = 0;
  #pragma unroll
  for (int k=1;k<14;k++) if (blk >= J.start[k]) j = k;
  size_t idx = (size_t)(blk - J.start[j])*2048 + (size_t)tid*8;
  const f32x4* ps = (const f32x4*)(J.s[j] + idx);
  f32x4 a = ps[0], b = ps[1];
  s16x8 o;
  #pragma unroll
  for (int i=0;i<4;i++){ o[i]=(short)f2b(a[i]); o[4+i]=(short)f2b(b[i]); }
  *(s16x8*)(J.d[j] + idx) = o;
}

// ---------------- enc weights f32 -> fp8 (scale x64) ----------------
struct Cvt8Jobs { const float* s[4]; u8* d[4]; int start[4]; };

__global__ __launch_bounds__(256) void cvt_w8(Cvt8Jobs J){
  int blk = blockIdx.x, tid = threadIdx.x;
  int j = 0;
  #pragma unroll
  for (int k=1;k<4;k++) if (blk >= J.start[k]) j = k;
  size_t idx = (size_t)(blk - J.start[j])*2048 + (size_t)tid*8;
  const f32x4* ps = (const f32x4*)(J.s[j] + idx);
  f32x4 a = ps[0], b = ps[1];
  int w0 = __builtin_amdgcn_cvt_pk_fp8_f32(a[0]*64.f, a[1]*64.f, 0, false);
  w0 = __builtin_amdgcn_cvt_pk_fp8_f32(a[2]*64.f, a[3]*64.f, w0, true);
  int w1 = __builtin_amdgcn_cvt_pk_fp8_f32(b[0]*64.f, b[1]*64.f, 0, false);
  w1 = __builtin_amdgcn_cvt_pk_fp8_f32(b[2]*64.f, b[3]*64.f, w1, true);
  i32x2 o; o[0]=w0; o[1]=w1;
  *(i32x2*)(J.d[j] + idx) = o;
}

__global__ __launch_bounds__(256) void tr_w2d(const u16* __restrict__ in, u16* __restrict__ out){
  int idx = blockIdx.x*256 + threadIdx.x;  // 32768
  int r = idx>>7, p = idx&127;
  out[idx] = in[p*256 + r];
}

__global__ __launch_bounds__(256) void pb_k(const float* __restrict__ Wihd, const float* __restrict__ b2d,
                                            float* __restrict__ pb){
  int g = blockIdx.x*256 + threadIdx.x;    // 2048
  const float* row = Wihd + (size_t)g*384 + 256;
  float s = 0.f;
  for (int p=0;p<128;p++) s += row[p]*b2d[p];
  pb[g] = s;
}

// ---------------- LayerNorm stats ----------------
__global__ __launch_bounds__(256) void ln_stats(const float* __restrict__ x,
                                                float* __restrict__ mu, float* __restrict__ rstd){
  int b = blockIdx.x;
  const float* xb = x + (size_t)b*32768;
  float s1=0.f, s2=0.f;
  for (int i = threadIdx.x*4; i < 32768; i += 256*4){
    f32x4 v = *(const f32x4*)(xb+i);
    #pragma unroll
    for (int j=0;j<4;j++){ float f = v[j]; s1+=f; s2+=f*f; }
  }
  #pragma unroll
  for (int o=32;o>0;o>>=1){ s1 += __shfl_down(s1,o); s2 += __shfl_down(s2,o); }
  __shared__ float r1[4], r2[4];
  int w = threadIdx.x>>6;
  if ((threadIdx.x&63)==0){ r1[w]=s1; r2[w]=s2; }
  __syncthreads();
  if (threadIdx.x==0){
    float a=0.f,c=0.f;
    for (int i=0;i<4;i++){ a+=r1[i]; c+=r2[i]; }
    float m=a/32768.f, v=c/32768.f-m*m;
    mu[b]=m; rstd[b]=1.f/sqrtf(v+1e-5f);
  }
}

// ---------------- fused LN + encode GEMM (writes fp8 xe, scale x16) ----------------
__global__ __launch_bounds__(256) void ln_gemm(const float* __restrict__ x,
    const float* __restrict__ mu, const float* __restrict__ rstd,
    const float* __restrict__ g, const float* __restrict__ bn,
    const u16* __restrict__ Wb, const float* __restrict__ be, u8* __restrict__ xe){
  __shared__ __align__(16) u16 As[128*32];
  __shared__ __align__(16) u16 Ws[128*32];
  int tid=threadIdx.x, lane=tid&63, wid=tid>>6;
  int wr=wid>>1, wc=wid&1;
  long m0=(long)blockIdx.y*128, n0=(long)blockIdx.x*128;
  int lr=lane&15, lk=(lane>>4)*8;
  f32x4 acc[4][4];
  #pragma unroll
  for (int i=0;i<4;i++)
    #pragma unroll
    for (int j=0;j<4;j++) acc[i][j]=(f32x4){0.f,0.f,0.f,0.f};

  for (int k0=0;k0<128;k0+=32){
    __syncthreads();
    #pragma unroll
    for (int c=tid;c<512;c+=256){
      int row=c>>2, kb=(c&3)*8;
      long R=m0+row;
      int b=(int)(R>>8), tt=(int)(R&255);
      float m=mu[b], rs=rstd[b];
      const f32x4* px=(const f32x4*)(x + R*128 + k0+kb);
      const f32x4* pg=(const f32x4*)(g + tt*128 + k0+kb);
      const f32x4* pb=(const f32x4*)(bn + tt*128 + k0+kb);
      f32x4 x0=px[0], x1=px[1], g0=pg[0], g1=pg[1], b0=pb[0], b1=pb[1];
      s16x8 o;
      #pragma unroll
      for (int j=0;j<4;j++){
        o[j]   = (short)f2b((x0[j]-m)*rs*g0[j] + b0[j]);
        o[4+j] = (short)f2b((x1[j]-m)*rs*g1[j] + b1[j]);
      }
      *(s16x8*)(As + row*32 + kb) = o;
    }
    #pragma unroll
    for (int c=tid;c<512;c+=256){
      int row=c>>2, kb=(c&3)*8;
      *(s16x8*)(Ws + row*32 + kb) = *(const s16x8*)(Wb + (n0+row)*128 + k0+kb);
    }
    __syncthreads();
    bv8 af[4], bf[4];
    #pragma unroll
    for (int i=0;i<4;i++) af[i] = ldf(As + (wr*64+i*16+lr)*32 + lk);
    #pragma unroll
    for (int j=0;j<4;j++) bf[j] = ldf(Ws + (wc*64+j*16+lr)*32 + lk);
    #pragma unroll
    for (int i=0;i<4;i++)
      #pragma unroll
      for (int j=0;j<4;j++) acc[i][j] = mfma16(af[i], bf[j], acc[i][j]);
  }
  #pragma unroll
  for (int i=0;i<4;i++)
    #pragma unroll
    for (int j=0;j<4;j++)
      #pragma unroll
      for (int r=0;r<4;r++){
        int m = wr*64+i*16+(lane>>4)*4+r;
        int n = wc*64+j*16+lr;
        float v = acc[i][j][r] + be[n0+n];
        xe[(m0+m)*256 + n0+n] = f2e4(fmaxf(v,0.f)*16.f);
      }
}

// ---------------- generic GEMM ----------------
template<int BM, int BN, bool RELU, bool OUTF32>
__global__ __launch_bounds__(256) void gemm_bt(const u16* __restrict__ A, int lda,
                                               const u16* __restrict__ W, int ldw,
                                               const float* __restrict__ bias1, const float* __restrict__ bias2,
                                               u16* __restrict__ Cb, float* __restrict__ Cf, int ldc, int K){
  constexpr int BK=32;
  constexpr int FM=BM/32, FN=BN/32;
  __shared__ __align__(16) u16 As[BM*BK];
  __shared__ __align__(16) u16 Ws[BN*BK];
  int tid=threadIdx.x, lane=tid&63, wid=tid>>6;
  int wr=wid>>1, wc=wid&1;
  long m0=(long)blockIdx.y*BM, n0=(long)blockIdx.x*BN;
  int lr=lane&15, lk=(lane>>4)*8;
  f32x4 acc[FM][FN];
  #pragma unroll
  for (int i=0;i<FM;i++)
    #pragma unroll
    for (int j=0;j<FN;j++) acc[i][j] = (f32x4){0.f,0.f,0.f,0.f};
  for (int k0=0;k0<K;k0+=BK){
    __syncthreads();
    #pragma unroll
    for (int c=tid;c<BM*4;c+=256){
      int row=c>>2, kb=(c&3)*8;
      *(s16x8*)(As + row*BK + kb) = *(const s16x8*)(A + (m0+row)*lda + k0+kb);
    }
    #pragma unroll
    for (int c=tid;c<BN*4;c+=256){
      int row=c>>2, kb=(c&3)*8;
      *(s16x8*)(Ws + row*BK + kb) = *(const s16x8*)(W + (n0+row)*ldw + k0+kb);
    }
    __syncthreads();
    bv8 af[FM], bf[FN];
    #pragma unroll
    for (int i=0;i<FM;i++) af[i] = ldf(As + (wr*(BM/2)+i*16+lr)*BK + lk);
    #pragma unroll
    for (int j=0;j<FN;j++) bf[j] = ldf(Ws + (wc*(BN/2)+j*16+lr)*BK + lk);
    #pragma unroll
    for (int i=0;i<FM;i++)
      #pragma unroll
      for (int j=0;j<FN;j++) acc[i][j] = mfma16(af[i], bf[j], acc[i][j]);
  }
  #pragma unroll
  for (int i=0;i<FM;i++)
    #pragma unroll
    for (int j=0;j<FN;j++)
      #pragma unroll
      for (int r=0;r<4;r++){
        int m = wr*(BM/2)+i*16+(lane>>4)*4+r;
        int n = wc*(BN/2)+j*16+lr;
        float v = acc[i][j][r];
        if (bias1) v += bias1[n0+n];
        if (bias2) v += bias2[n0+n];
        if (RELU) v = fmaxf(v,0.f);
        if (OUTF32) Cf[(m0+m)*ldc + n0+n] = v;
        else        Cb[(m0+m)*ldc + n0+n] = f2b(v);
      }
}

// ================= persistent encoder (fp8 datapath; 512 threads, 8 waves x 16 samples) =================
// grid 256: grp = bx&7 (dir*4+bt), kc = bx>>3 (16 cells)
// weights x64, activations x16 -> acc/1024. Cell state f32, pooled bf16 (unchanged).
struct EncP {
  const u8* xe; const int* lens;
  const u8 *Wihf8,*Whhf8,*Wihb8,*Whhb8;
  const float *bif,*bhf,*bib,*bhb;
  u8 *hf0,*hf1,*hb0,*hb1;
  u16* pooled;
  unsigned* flags;
};

__global__ __launch_bounds__(512,1) void enc_persist(EncP P){
  __shared__ __align__(16) u8 Wl[64*776];   // [64 gate rows][768 K fp8], stride 776B
  __shared__ __align__(4)  u8 Hs[128*16];   // h as fp8 x16
  const int tid=threadIdx.x, lane=tid&63, w=tid>>6;   // w in 0..7
  const int bx=blockIdx.x;
  const int grp=bx&7, kc=bx>>3;
  const int dir=grp>>2, bt=grp&3;
  const int lr=lane&15, q8=(lane>>4)*8;
  unsigned* flags = P.flags + grp*2048;
  const u8* Wih8 = dir? P.Wihb8 : P.Wihf8;
  const u8* Whh8 = dir? P.Whhb8 : P.Whhf8;
  const float* bi = dir? P.bib : P.bif;
  const float* bh = dir? P.bhb : P.bhf;
  u8* h0 = dir? P.hb0 : P.hf0;
  u8* h1 = dir? P.hb1 : P.hf1;

  for (int idx=tid; idx<64*96; idx+=512){
    int row=idx/96, col8=(idx%96)*8;
    int g=row>>4, c=row&15;
    size_t grow=(size_t)(g*512 + kc*16 + c);
    const u8* src = (col8<256)? (Wih8 + grow*256 + col8) : (Whh8 + grow*512 + (col8-256));
    *(u64*)(Wl + (size_t)row*776 + col8) = *(const u64*)src;
  }
  const int cg = kc*16 + lr;
  const float b_i=bi[cg]+bh[cg], b_f=bi[512+cg]+bh[512+cg];
  const float b_g=bi[1024+cg]+bh[1024+cg], b_o=bi[1536+cg]+bh[1536+cg];
  const float gsc = 1.f/1024.f;
  const int r0 = w*16 + lr;
  const int slen0 = P.lens[bt*128+r0];
  const u8* xb0 = P.xe + (size_t)(bt*128+r0)*256;
  int elen[4]; float cs[4], hh[4], asum[4];
  #pragma unroll
  for (int r=0;r<4;r++){
    int m=w*16+(lane>>4)*4+r;
    elen[r]=P.lens[bt*128+m];
    cs[r]=0.f; hh[r]=0.f; asum[r]=0.f;
  }
  __syncthreads();   // weights staged

  u64 rx[8];
  auto issue_rx=[&](int t_){
    int tt = dir? max(slen0-1-t_,0) : t_;
    const u8* xr = xb0 + (size_t)tt*256;
    #pragma unroll
    for (int j=0;j<8;j++) gldc8(rx[j], xr + j*32 + q8);
  };
  issue_rx(0);

  for (int t=0;t<256;t++){
    const u8* hp = (t&1)? h1 : h0;
    u8*       hn = (t&1)? h0 : h1;
    waitflags(flags, 0, 32, (unsigned)t);
    // issue all 16 h fragment loads (sc1)
    u64 fb[16];
    {
      const u8* hr = hp + (size_t)(bt*128+r0)*512;
      #pragma unroll
      for (int j=0;j<16;j++) gld8(fb[j], hr + j*32 + q8);
    }
    wvm<16>();   // drains rx (issued earlier; vmcnt FIFO), waits for no h loads
    f32x4 acc[4];
    #pragma unroll
    for (int g=0;g<4;g++) acc[g]=(f32x4){0.f,0.f,0.f,0.f};
    // x-part (K=256) from prefetched registers, under h-load latency
    #pragma unroll
    for (int j=0;j<8;j++){
      u64 a = rx[j];
      #pragma unroll
      for (int g=0;g<4;g++){
        u64 b = *(const u64*)(Wl + (size_t)(g*16+lr)*776 + j*32 + q8);
        acc[g]=mfma8(a,b,acc[g]);
      }
    }
    wvm<8>();
    #pragma unroll
    for (int j=0;j<8;j++){
      u64 a = fb[j];
      #pragma unroll
      for (int g=0;g<4;g++){
        u64 b = *(const u64*)(Wl + (size_t)(g*16+lr)*776 + 256 + j*32 + q8);
        acc[g]=mfma8(a,b,acc[g]);
      }
    }
    wvm<0>();
    #pragma unroll
    for (int j=8;j<16;j++){
      u64 a = fb[j];
      #pragma unroll
      for (int g=0;g<4;g++){
        u64 b = *(const u64*)(Wl + (size_t)(g*16+lr)*776 + 256 + j*32 + q8);
        acc[g]=mfma8(a,b,acc[g]);
      }
    }
    // cell (f32)
    #pragma unroll
    for (int r=0;r<4;r++){
      int m=w*16+(lane>>4)*4+r;
      if (t<elen[r]){
        float iv=sigm(acc[0][r]*gsc+b_i), fv=sigm(acc[1][r]*gsc+b_f);
        float gv=tanh_(acc[2][r]*gsc+b_g), ov=sigm(acc[3][r]*gsc+b_o);
        float c2=fv*cs[r]+iv*gv, h2v=ov*tanh_(c2);
        cs[r]=c2; hh[r]=h2v; asum[r]+=h2v;
      }
      Hs[m*16+lr]=f2e4(hh[r]*16.f);
    }
    __syncthreads();
    {
      int sm=tid>>2, pt=tid&3;   // 512 threads: 128 samples x 4B chunks
      gst4(hn + (size_t)(bt*128+sm)*512 + kc*16 + pt*4, *(const u32*)(Hs + sm*16 + pt*4));
    }
    arrive(flags, kc, (unsigned)(t+1));
    if (t<255) issue_rx(t+1);
  }
  #pragma unroll
  for (int r=0;r<4;r++){
    int m=w*16+(lane>>4)*4+r;
    P.pooled[(size_t)(bt*128+m)*1024 + (size_t)dir*512 + cg]=f2b(asum[r]/(float)elen[r]);
  }
}

// ================= persistent decoder (r12-proven, unchanged bf16) =================
struct DecP {
  const u16 *Whhd, *Wcmp, *W1d, *W2d;
  const float *gix, *gp0, *pb, *b1d, *b2d;
  u16 *h0,*h1,*r1a,*r1b;
  float* outd;
  unsigned* flags;
};

__global__ __launch_bounds__(256,1) void dec_persist(DecP P){
  __shared__ __align__(16) u16 Wh [64*520];
  __shared__ __align__(16) u16 WcL[64*264];
  __shared__ __align__(16) u16 F12[16*520];
  __shared__ __align__(16) u16 Hs[64*16];
  const int tid=threadIdx.x, lane=tid&63, w=tid>>6;
  const int bx=blockIdx.x;
  const int grp=bx&7, kc=bx>>3;
  const int g0 = grp*64;
  const int lr=lane&15, lk=(lane>>4)*8;
  unsigned* flags = P.flags + grp*2048;

  for (int idx=tid; idx<64*64; idx+=256){
    int row=idx>>6, col=(idx&63)*8;
    int g=row>>4, c=row&15;
    size_t grow=(size_t)(g*512+kc*16+c);
    *(s16x8*)(Wh + row*520 + col) = *(const s16x8*)(P.Whhd + grow*512 + col);
  }
  for (int idx=tid; idx<64*32; idx+=256){
    int row=idx>>5, col=(idx&31)*8;
    int g=row>>4, c=row&15;
    size_t grow=(size_t)(g*512+kc*16+c);
    *(s16x8*)(WcL + row*264 + col) = *(const s16x8*)(P.Wcmp + grow*256 + col);
  }
  if (kc<16){
    for (int idx=tid; idx<16*64; idx+=256){
      int rr=idx>>6, col=(idx&63)*8;
      *(s16x8*)(F12 + rr*520 + col) = *(const s16x8*)(P.W1d + (size_t)(kc*16+rr)*512 + col);
    }
  } else if (kc<24){
    for (int idx=tid; idx<16*32; idx+=256){
      int rr=idx>>5, col=(idx&31)*8;
      *(s16x8*)(F12 + rr*264 + col) = *(const s16x8*)(P.W2d + (size_t)((kc-16)*16+rr)*256 + col);
    }
  }
  float gx[4][4]; float pbr[4];
  #pragma unroll
  for (int g=0;g<4;g++)
    #pragma unroll
    for (int r=0;r<4;r++){
      int m=w*16+(lane>>4)*4+r;
      gx[g][r]=P.gix[(size_t)(g0+m)*2048 + (size_t)g*512 + kc*16 + lr];
    }
  #pragma unroll
  for (int g=0;g<4;g++) pbr[g] = P.pb[(size_t)g*512 + kc*16 + lr];
  const float b1=(kc<16)? P.b1d[kc*16+lr] : 0.f;
  const float b2=(kc>=16&&kc<24)? P.b2d[(kc-16)*16+lr] : 0.f;
  const int ar = w*16 + lr;
  float cs[4];
  f32x4 gh[4];
  #pragma unroll
  for (int r=0;r<4;r++) cs[r]=0.f;
  #pragma unroll
  for (int g=0;g<4;g++) gh[g]=(f32x4){0.f,0.f,0.f,0.f};
  __syncthreads();   // weights staged

  for (int t=0;t<256;t++){
    const u16* r1rd = (t&1)? P.r1b : P.r1a;
    u16* hn = (t&1)? P.h0 : P.h1;
    f32x4 acc[4];
    if (t==0){
      #pragma unroll
      for (int g=0;g<4;g++)
        #pragma unroll
        for (int r=0;r<4;r++){
          int m=w*16+(lane>>4)*4+r;
          acc[g][r] = gx[g][r] + P.gp0[(size_t)(g0+m)*2048 + (size_t)g*512 + kc*16 + lr];
        }
    } else {
      waitflags(flags, 32, 16, (unsigned)t);   // r1_t ready
      #pragma unroll
      for (int g=0;g<4;g++){
        acc[g] = (f32x4){gx[g][0]+pbr[g], gx[g][1]+pbr[g], gx[g][2]+pbr[g], gx[g][3]+pbr[g]};
        acc[g] = acc[g] + gh[g];
      }
      const u16* rb = r1rd + (size_t)(g0+ar)*256;
      s16x8 fb[8];
      #pragma unroll
      for (int k=0;k<4;k++){
        gld16(fb[k*2],   rb + k*64 + lk);
        gld16(fb[k*2+1], rb + k*64 + 32 + lk);
      }
      wvm<0>();
      #pragma unroll
      for (int k=0;k<4;k++)
        #pragma unroll
        for (int kk=0;kk<2;kk++){
          bv8 a=cvt(fb[k*2+kk]);
          #pragma unroll
          for (int g=0;g<4;g++){
            bv8 bf=ldf(WcL + (g*16+lr)*264 + k*64 + kk*32 + lk);
            acc[g]=mfma16(a,bf,acc[g]);
          }
        }
    }
    // cell
    #pragma unroll
    for (int r=0;r<4;r++){
      float iv=sigm(acc[0][r]), fv=sigm(acc[1][r]);
      float gv=tanh_(acc[2][r]), ov=sigm(acc[3][r]);
      float c2=fv*cs[r]+iv*gv, h2v=ov*tanh_(c2);
      cs[r]=c2;
      int m=w*16+(lane>>4)*4+r;
      Hs[m*16+lr]=f2b(h2v);
    }
    __syncthreads();
    {
      int sm=tid>>2, pt=tid&3;
      gst8(hn + (size_t)(g0+sm)*512 + kc*16 + pt*4, *(const u64*)(Hs + sm*16 + pt*4));
    }
    arrive(flags, kc, (unsigned)(t+1));      // G flag
    if (kc>=16 && kc<24 && t>0){
      const u16* rb = r1rd + (size_t)(g0+ar)*256;
      f32x4 fa2=(f32x4){0.f,0.f,0.f,0.f};
      s16x8 fb[8];
      #pragma unroll
      for (int k=0;k<4;k++){
        gld16(fb[k*2],   rb + k*64 + lk);
        gld16(fb[k*2+1], rb + k*64 + 32 + lk);
      }
      wvm<0>();
      #pragma unroll
      for (int k=0;k<4;k++)
        #pragma unroll
        for (int kk=0;kk<2;kk++){
          bv8 a=cvt(fb[k*2+kk]);
          bv8 bf=ldf(F12 + lr*264 + k*64 + kk*32 + lk);
          fa2=mfma16(a,bf,fa2);
        }
      int pc=(kc-16)*16+lr;
      #pragma unroll
      for (int r=0;r<4;r++){
        int m=w*16+(lane>>4)*4+r;
        __builtin_nontemporal_store(fa2[r]+b2, P.outd + (size_t)(g0+m)*32768 + (size_t)(t-1)*128 + pc);
      }
    }
    waitflags(flags, 0, 32, (unsigned)(t+1));     // h_{t+1} ready
    f32x4 gn[4]; f32x4 fa=(f32x4){0.f,0.f,0.f,0.f};
    #pragma unroll
    for (int g=0;g<4;g++) gn[g]=(f32x4){0.f,0.f,0.f,0.f};
    {
      const u16* hb = hn + (size_t)(g0+ar)*512;
      s16x8 fb[2][8];
      auto issue=[&](int b, int h4){
        const u16* p = hb + h4*256;
        #pragma unroll
        for (int k=0;k<4;k++){
          gld16(fb[b][k*2],   p + k*64 + lk);
          gld16(fb[b][k*2+1], p + k*64 + 32 + lk);
        }
      };
      issue(0,0); issue(1,1);
      #pragma unroll
      for (int h4=0;h4<2;h4++){
        if (h4==0) wvm<8>(); else wvm<0>();
        #pragma unroll
        for (int k=0;k<4;k++)
          #pragma unroll
          for (int kk=0;kk<2;kk++){
            bv8 a=cvt(fb[h4][k*2+kk]);
            int col = h4*256 + k*64 + kk*32;
            #pragma unroll
            for (int g=0;g<4;g++){
              bv8 bf=ldf(Wh + (g*16+lr)*520 + col + lk);
              gn[g]=mfma16(a,bf,gn[g]);
            }
            if (kc<16){
              bv8 bf=ldf(F12 + lr*520 + col + lk);
              fa=mfma16(a,bf,fa);
            }
          }
      }
    }
    #pragma unroll
    for (int g=0;g<4;g++) gh[g]=gn[g];
    if (kc<16){
      u16* r1w = (t&1)? P.r1a : P.r1b;     // parity (t+1)&1
      #pragma unroll
      for (int r=0;r<4;r++){
        int m=w*16+(lane>>4)*4+r;
        Hs[m*16+lr]=f2b(fmaxf(fa[r]+b1,0.f));
      }
      __syncthreads();
      {
        int sm=tid>>2, pt=tid&3;
        gst8(r1w + (size_t)(g0+sm)*256 + kc*16 + pt*4, *(const u64*)(Hs + sm*16 + pt*4));
      }
      arrive(flags, 32+kc, (unsigned)(t+1));   // F flag
    }
  }
  // epilogue: pose_256 -> outd[255]
  if (kc>=16 && kc<24){
    waitflags(flags, 32, 16, 256u);
    const u16* rb = P.r1a + (size_t)(g0+ar)*256;  // r1_256 parity 0
    f32x4 fa2=(f32x4){0.f,0.f,0.f,0.f};
    s16x8 fb[8];
    #pragma unroll
    for (int k=0;k<4;k++){
      gld16(fb[k*2],   rb + k*64 + lk);
      gld16(fb[k*2+1], rb + k*64 + 32 + lk);
    }
    wvm<0>();
    #pragma unroll
    for (int k=0;k<4;k++)
      #pragma unroll
      for (int kk=0;kk<2;kk++){
        bv8 a=cvt(fb[k*2+kk]);
        bv8 bf=ldf(F12 + lr*264 + k*64 + kk*32 + lk);
        fa2=mfma16(a,bf,fa2);
      }
    int pc=(kc-16)*16+lr;
    #pragma unroll
    for (int r=0;r<4;r++){
      int m=w*16+(lane>>4)*4+r;
      __builtin_nontemporal_store(fa2[r]+b2, P.outd + (size_t)(g0+m)*32768 + (size_t)255*128 + pc);
    }
  }
}

__global__ __launch_bounds__(512) void len_cast(const int* __restrict__ lens, float* __restrict__ out){
  int i = threadIdx.x;
  if (i < 512) out[i] = (float)lens[i];
}

// ============================== host ==============================
extern "C" void kernel_launch(void* const* d_in, const int* in_sizes, int n_in,
                              void* d_out, int out_size, void* d_ws, size_t ws_size,
                              hipStream_t stream){
  (void)in_sizes; (void)n_in; (void)out_size; (void)ws_size;
  const float* x      = (const float*)d_in[0];
  const int*   lens   = (const int*)d_in[1];
  const float* ng     = (const float*)d_in[2];
  const float* nb     = (const float*)d_in[3];
  const float* We     = (const float*)d_in[4];
  const float* be     = (const float*)d_in[5];
  const float* Wih_f  = (const float*)d_in[6];
  const float* Whh_f  = (const float*)d_in[7];
  const float* bih_f  = (const float*)d_in[8];
  const float* bhh_f  = (const float*)d_in[9];
  const float* Wih_b  = (const float*)d_in[10];
  const float* Whh_b  = (const float*)d_in[11];
  const float* bih_b  = (const float*)d_in[12];
  const float* bhh_b  = (const float*)d_in[13];
  const float* W1e    = (const float*)d_in[14];
  const float* b1e    = (const float*)d_in[15];
  const float* W2e    = (const float*)d_in[16];
  const float* b2e    = (const float*)d_in[17];
  const float* Wd     = (const float*)d_in[18];
  const float* bd     = (const float*)d_in[19];
  const float* Wp1    = (const float*)d_in[20];
  const float* bp1    = (const float*)d_in[21];
  const float* Wp2    = (const float*)d_in[22];
  const float* bp2    = (const float*)d_in[23];
  const float* Wih_d  = (const float*)d_in[24];
  const float* Whh_d  = (const float*)d_in[25];
  const float* bih_d  = (const float*)d_in[26];
  const float* bhh_d  = (const float*)d_in[27];
  const float* W1d    = (const float*)d_in[28];
  const float* b1d    = (const float*)d_in[29];
  const float* W2d    = (const float*)d_in[30];
  const float* b2d    = (const float*)d_in[31];

  char* p = (char*)d_ws;
  auto carve = [&](size_t bytes)->void*{ void* r=(void*)p; p += (bytes+255)&~(size_t)255; return r; };
  float* mu   = (float*)carve(512*4);
  float* rstd = (float*)carve(512*4);
  u8* xe8     = (u8*)carve((size_t)33554432);        // [B*T,256] fp8 (x16)
  u16* wWe  = (u16*)carve(32768*2);
  u16* wIhf = (u16*)carve(524288*2);
  u16* wHhf = (u16*)carve(1048576*2);
  u16* wIhb = (u16*)carve(524288*2);
  u16* wHhb = (u16*)carve(1048576*2);
  u16* wW1e = (u16*)carve(524288*2);
  u16* wW2e = (u16*)carve(131072*2);
  u16* wWd  = (u16*)carve(65536*2);
  u16* wWp1 = (u16*)carve(65536*2);
  u16* wWp2 = (u16*)carve(32768*2);
  u16* wIhd = (u16*)carve(786432*2);
  u16* wHhd = (u16*)carve(1048576*2);
  u16* wW1d = (u16*)carve(131072*2);
  u16* wW2d = (u16*)carve(32768*2);
  u16* wW2dT  = (u16*)carve(32768*2);
  u16* wWcomp = (u16*)carve(524288*2);
  u8* wIhf8 = (u8*)carve(524288);
  u8* wHhf8 = (u8*)carve(1048576);
  u8* wIhb8 = (u8*)carve(524288);
  u8* wHhb8 = (u8*)carve(1048576);
  float* pbv  = (float*)carve(2048*4);
  float* gp0f = (float*)carve((size_t)1048576*4);
  u8* hf0  = (u8*)carve(262144);
  u8* hf1  = (u8*)carve(262144);
  u8* hb0  = (u8*)carve(262144);
  u8* hb1  = (u8*)carve(262144);
  u16* hd0  = (u16*)carve(524288);
  u16* hd1  = (u16*)carve(524288);
  u16* r1a  = (u16*)carve(262144);
  u16* r1b  = (u16*)carve(262144);
  u16* pooled = (u16*)carve(1048576);
  u16* out1   = (u16*)carve(524288);
  u16* zlat   = (u16*)carve(262144);
  u16* x0     = (u16*)carve(262144);
  u16* t0     = (u16*)carve(262144);
  float* gix  = (float*)carve(4194304);
  u16* pose   = (u16*)carve(131072);
  unsigned* barflags = (unsigned*)carve(16*2048*4);

  float* out_x   = (float*)d_out;
  float* out_dec = out_x + 16777216;
  float* out_len = out_x + 33554432;

  hipMemcpyAsync(out_x, x, (size_t)16777216*4, hipMemcpyDeviceToDevice, stream);
  hipMemsetAsync(hf0,0,262144,stream);
  hipMemsetAsync(hb0,0,262144,stream);
  hipMemsetAsync(barflags,0,16*2048*4,stream);

  CvtJobs J;
  const float* srcs[14] = {We,Wih_f,Whh_f,Wih_b,Whh_b,W1e,W2e,Wd,Wp1,Wp2,Wih_d,Whh_d,W1d,W2d};
  u16* dsts[14] = {wWe,wIhf,wHhf,wIhb,wHhb,wW1e,wW2e,wWd,wWp1,wWp2,wIhd,wHhd,wW1d,wW2d};
  int ns[14] = {32768,524288,1048576,524288,1048576,524288,131072,65536,65536,32768,786432,1048576,131072,32768};
  int blk=0;
  for (int i=0;i<14;i++){ J.s[i]=srcs[i]; J.d[i]=dsts[i]; J.start[i]=blk; blk += ns[i]/2048; }
  cvt_w<<<blk,256,0,stream>>>(J);

  Cvt8Jobs J8;
  const float* s8[4] = {Wih_f,Whh_f,Wih_b,Whh_b};
  u8* d8[4] = {wIhf8,wHhf8,wIhb8,wHhb8};
  int n8[4] = {524288,1048576,524288,1048576};
  int blk8=0;
  for (int i=0;i<4;i++){ J8.s[i]=s8[i]; J8.d[i]=d8[i]; J8.start[i]=blk8; blk8 += n8[i]/2048; }
  cvt_w8<<<blk8,256,0,stream>>>(J8);

  tr_w2d<<<128,256,0,stream>>>(wW2d, wW2dT);
  pb_k<<<8,256,0,stream>>>(Wih_d, b2d, pbv);
  gemm_bt<64,64,false,false><<<dim3(4,32),256,0,stream>>>(wIhd+256,384, wW2dT,128, nullptr,nullptr, wWcomp,nullptr,256,128);

  ln_stats<<<512,256,0,stream>>>(x,mu,rstd);
  ln_gemm<<<dim3(2,1024),256,0,stream>>>(x,mu,rstd,ng,nb,wWe,be,xe8);

  EncP EP = {xe8,lens,wIhf8,wHhf8,wIhb8,wHhb8,bih_f,bhh_f,bih_b,bhh_b,hf0,hf1,hb0,hb1,pooled,barflags};
  {
    void* ea[] = {&EP};
    if (hipLaunchCooperativeKernel((void*)enc_persist, dim3(256), dim3(512), ea, 0, stream) != hipSuccess)
      enc_persist<<<256,512,0,stream>>>(EP);
  }

  gemm_bt<64,64,true ,false><<<dim3(8,8),256,0,stream>>>(pooled,1024,wW1e,1024,b1e,nullptr,out1,nullptr,512,1024);
  gemm_bt<64,64,false,false><<<dim3(4,8),256,0,stream>>>(out1,512,wW2e,512,b2e,nullptr,zlat,nullptr,256,512);
  gemm_bt<64,64,true ,false><<<dim3(4,8),256,0,stream>>>(zlat,256,wWd,256,bd,nullptr,x0,nullptr,256,256);
  gemm_bt<64,64,true ,false><<<dim3(4,8),256,0,stream>>>(x0,256,wWp1,256,bp1,nullptr,t0,nullptr,256,256);
  gemm_bt<64,64,false,false><<<dim3(2,8),256,0,stream>>>(t0,256,wWp2,256,bp2,nullptr,pose,nullptr,128,256);
  gemm_bt<64,128,false,true><<<dim3(16,8),256,0,stream>>>(x0,256,wIhd,384,bih_d,bhh_d,nullptr,gix,2048,256);
  gemm_bt<64,128,false,true><<<dim3(16,8),256,0,stream>>>(pose,128,wIhd+256,384,nullptr,nullptr,nullptr,gp0f,2048,128);

  DecP DP = {wHhd,wWcomp,wW1d,wW2d, gix,gp0f,pbv,b1d,b2d, hd0,hd1,r1a,r1b, out_dec, barflags + 8*2048};
  {
    void* da[] = {&DP};
    if (hipLaunchCooperativeKernel((void*)dec_persist, dim3(256), dim3(256), da, 0, stream) != hipSuccess)
      dec_persist<<<256,256,0,stream>>>(DP);
  }

  len_cast<<<1,512,0,stream>>>(lens,out_len);
}